// Round 16
// baseline (224.143 us; speedup 1.0000x reference)
//
#include <hip/hip_runtime.h>
#include <stdint.h>
#include <stddef.h>

typedef __attribute__((ext_vector_type(8))) short short8;
typedef __attribute__((ext_vector_type(4))) float floatx4;
typedef unsigned short ushort_t;

__device__ __forceinline__ ushort_t f2bf(float f) {
    union { float f; uint32_t u; } v; v.f = f;
    return (ushort_t)((v.u + 0x7fffu + ((v.u >> 16) & 1u)) >> 16);
}
__device__ __forceinline__ float bf2f(ushort_t u) {
    union { uint32_t u; float f; } v; v.u = ((uint32_t)u) << 16; return v.f;
}

// async global->LDS 16B staging (m97). LDS dest = wave-uniform base + lane*16.
__device__ __forceinline__ void load16_lds(const ushort_t* g, short* l) {
    __builtin_amdgcn_global_load_lds((const __attribute__((address_space(1))) void*)g,
                                     (__attribute__((address_space(3))) void*)l, 16, 0, 0);
}

enum { EPI_SPLIT = 0, EPI_SOFTPLUS = 1, EPI_OUT = 2, EPI_PARTIAL = 3 };

// Convert x + 4 weights fp32 -> bf16 in one launch.
__global__ __launch_bounds__(256)
void cvt5(const float* __restrict__ x, const float* __restrict__ win,
          const float* __restrict__ wx, const float* __restrict__ wdt,
          const float* __restrict__ wout,
          ushort_t* __restrict__ xb, ushort_t* __restrict__ winb,
          ushort_t* __restrict__ wxb, ushort_t* __restrict__ wdtb,
          ushort_t* __restrict__ woutb)
{
    int g = blockIdx.x * 256 + threadIdx.x;   // < 2179072 exactly
    const float* s; ushort_t* d; int off;
    if      (g < 524288)  { s = x;    d = xb;    off = g; }
    else if (g < 1572864) { s = win;  d = winb;  off = g - 524288; }
    else if (g < 1622016) { s = wx;   d = wxb;   off = g - 1572864; }
    else if (g < 1654784) { s = wdt;  d = wdtb;  off = g - 1622016; }
    else                  { s = wout; d = woutb; off = g - 1654784; }
    float4 v = reinterpret_cast<const float4*>(s)[off];
    union { ushort_t u[4]; uint2 q; } o;
    o.u[0] = f2bf(v.x); o.u[1] = f2bf(v.y); o.u[2] = f2bf(v.z); o.u[3] = f2bf(v.w);
    *reinterpret_cast<uint2*>(d + (size_t)off * 4) = o.q;
}

// C[m,n] = sum_k A[m,k] * B[n,k]  (bf16 operands, fp32 accum)
template<int BM, int BN, int BK, int WR, int WC, int EPI>
__global__ __launch_bounds__(256)
void gemm_bt(const ushort_t* __restrict__ A, int lda,
             const ushort_t* __restrict__ Bw, int ldb,
             float* __restrict__ out0,
             ushort_t* __restrict__ outg,   // EPI_SPLIT gate half (silu bf16)
             ushort_t* __restrict__ outc,   // EPI_SPLIT conv half (bf16)
             const float* __restrict__ bias,
             int N, int kchunk)
{
    constexpr int TM = BM / WR / 16;
    constexpr int TN = BN / WC / 16;
    static_assert(BM % (WR * 16) == 0 && BN % (WC * 16) == 0, "tile");
    static_assert((BM * BK) % 2048 == 0 && (BN * BK) % 2048 == 0, "stage");

    __shared__ __align__(16) short As[BM * BK];
    __shared__ __align__(16) short Bs[BN * BK];

    const int tid  = threadIdx.x;
    const int m0   = blockIdx.x * BM;
    const int n0   = blockIdx.y * BN;
    const int ks   = blockIdx.z;
    const int kbeg = ks * kchunk;

    const int w    = tid >> 6;
    const int lane = tid & 63;
    const int quad = lane >> 4;
    const int l16  = lane & 15;
    const int wr   = w / WC, wc = w % WC;
    const int wm   = wr * (BM / WR);
    const int wn   = wc * (BN / WC);

    floatx4 acc[TM][TN];
#pragma unroll
    for (int i = 0; i < TM; i++)
#pragma unroll
        for (int j = 0; j < TN; j++) acc[i][j] = (floatx4){0.f, 0.f, 0.f, 0.f};

    constexpr int nA = BM * BK / 2048;
    constexpr int nB = BN * BK / 2048;
    constexpr int CPR = BK / 8;

    for (int kb = kbeg; kb < kbeg + kchunk; kb += BK) {
        __syncthreads();
#pragma unroll
        for (int i = 0; i < nA; i++) {
            int c = i * 256 + tid;
            int r = c / CPR, kc = (c % CPR) * 8;
            load16_lds(A + (size_t)(m0 + r) * lda + kb + kc, &As[r * BK + kc]);
        }
#pragma unroll
        for (int i = 0; i < nB; i++) {
            int c = i * 256 + tid;
            int r = c / CPR, kc = (c % CPR) * 8;
            load16_lds(Bw + (size_t)(n0 + r) * ldb + kb + kc, &Bs[r * BK + kc]);
        }
        __syncthreads();
#pragma unroll
        for (int kk = 0; kk < BK / 32; kk++) {
            short8 af[TM], bfr[TN];
#pragma unroll
            for (int t = 0; t < TM; t++)
                af[t] = *reinterpret_cast<const short8*>(&As[(wm + t * 16 + l16) * BK + kk * 32 + quad * 8]);
#pragma unroll
            for (int u2 = 0; u2 < TN; u2++)
                bfr[u2] = *reinterpret_cast<const short8*>(&Bs[(wn + u2 * 16 + l16) * BK + kk * 32 + quad * 8]);
#pragma unroll
            for (int t = 0; t < TM; t++)
#pragma unroll
                for (int u2 = 0; u2 < TN; u2++)
                    acc[t][u2] = __builtin_amdgcn_mfma_f32_16x16x32_bf16(af[t], bfr[u2], acc[t][u2], 0, 0, 0);
        }
    }

#pragma unroll
    for (int t = 0; t < TM; t++) {
#pragma unroll
        for (int u2 = 0; u2 < TN; u2++) {
#pragma unroll
            for (int r = 0; r < 4; r++) {
                int row = m0 + wm + t * 16 + quad * 4 + r;
                int col = n0 + wn + u2 * 16 + l16;
                float val = acc[t][u2][r];
                if (EPI == EPI_SPLIT) {
                    val += bias[col];
                    if (col < 2048) {
                        outc[(size_t)row * 2048 + col] = f2bf(val);
                    } else {
                        float sr = val / (1.f + __expf(-val));
                        outg[(size_t)row * 2048 + col - 2048] = f2bf(sr);
                    }
                } else if (EPI == EPI_SOFTPLUS) {
                    val += bias[col];
                    float sp = fmaxf(val, 0.f) + __logf(1.f + __expf(-fabsf(val)));
                    out0[(size_t)row * N + col] = sp;
                } else if (EPI == EPI_OUT) {
                    val += bias[col];
                    out0[(size_t)row * N + col] = val;
                } else { // EPI_PARTIAL: split-K partials [ks][m][96]
                    out0[((size_t)ks * 2048 + row) * 96 + col] = val;
                }
            }
        }
    }
}

// depthwise causal conv (k=3) + silu. bf16 in, bf16 out.
__global__ __launch_bounds__(256)
void conv_silu(const ushort_t* __restrict__ xc, const float* __restrict__ cw,
               const float* __restrict__ cb, ushort_t* __restrict__ ub)
{
    int id = blockIdx.x * 256 + threadIdx.x;   // 2048 * 512
    int m  = id >> 9;
    int d4 = (id & 511) * 4;
    int l  = m & 1023;

    union { uint2 q; ushort_t u[4]; } a, b, c;
    a.q = *reinterpret_cast<const uint2*>(xc + (size_t)m * 2048 + d4);
    if (l >= 1) b.q = *reinterpret_cast<const uint2*>(xc + (size_t)(m - 1) * 2048 + d4);
    else        { b.q.x = 0; b.q.y = 0; }
    if (l >= 2) c.q = *reinterpret_cast<const uint2*>(xc + (size_t)(m - 2) * 2048 + d4);
    else        { c.q.x = 0; c.q.y = 0; }

    union { ushort_t u[4]; uint2 q; } o;
#pragma unroll
    for (int j = 0; j < 4; j++) {
        int d = d4 + j;
        float v = cb[d] + cw[d * 3 + 0] * bf2f(c.u[j]) + cw[d * 3 + 1] * bf2f(b.u[j])
                        + cw[d * 3 + 2] * bf2f(a.u[j]);
        o.u[j] = f2bf(v / (1.f + __expf(-v)));
    }
    *reinterpret_cast<uint2*>(ub + (size_t)m * 2048 + d4) = o.q;
}

// reduce split-K=8 partials -> xp fp32 (2048 x 96) and dlt bf16 (2048 x 64)
__global__ __launch_bounds__(256)
void xp_reduce(const float* __restrict__ part, float* __restrict__ xp, ushort_t* __restrict__ dltb)
{
    int e = blockIdx.x * 256 + threadIdx.x;    // < 2048*96 exactly
    float s = 0.f;
#pragma unroll
    for (int ks = 0; ks < 8; ks++) s += part[(size_t)ks * 2048 * 96 + e];
    xp[e] = s;
    int n = e % 96, m = e / 96;
    if (n < 64) dltb[(size_t)m * 64 + n] = f2bf(s);
}

// Chunked selective scan — two-pass structure (28 VGPRs measured, 44.8 us,
// zero bank conflicts). DO NOT add phase-crossing register arrays (r10/r11/
// r12 all spilled to scratch, 8-30x slowdowns).
// Block = 1024 thr = 16 waves, one 256-token chunk x 32 channels.
// lane&31 = channel, lane>>5 = state-half h. Wave w owns t in [16w,16w+16).
__global__ __launch_bounds__(1024, 8)
void scan_kernel(const float* __restrict__ delta, const ushort_t* __restrict__ ub,
                 const float* __restrict__ xp, const float* __restrict__ A_log,
                 const ushort_t* __restrict__ sgb, ushort_t* __restrict__ ygb)
{
    __shared__ __align__(16) float Bsh[256 * 16];
    __shared__ __align__(16) float Csh[256 * 16];
    __shared__ float sQ[16][32][17];
    __shared__ float sS[16][32];

    const int tid  = threadIdx.x;
    const int w    = tid >> 6;                // wave = time segment
    const int lane = tid & 63;
    const int dl   = lane & 31;               // channel within tile
    const int h    = lane >> 5;               // state half
    const int d    = blockIdx.x * 32 + dl;
    const int c    = blockIdx.y;              // (batch<<2)|chunk
    const int mbase = (c >> 2) * 1024 + (c & 3) * 256;

    {   // stage B (xp cols 64..79) / C (80..95): 4 threads per row
        int r = tid >> 2, part = tid & 3;
        const float4* rp = reinterpret_cast<const float4*>(xp + (size_t)(mbase + r) * 96 + 64);
        reinterpret_cast<float4*>(Bsh + r * 16)[part] = rp[part];
        reinterpret_cast<float4*>(Csh + r * 16)[part] = rp[part + 4];
    }

    float Av[8];
    {
        const float4* ap = reinterpret_cast<const float4*>(A_log + (size_t)d * 16 + h * 8);
        float4 a0 = ap[0], a1 = ap[1];
        Av[0] = -__expf(a0.x); Av[1] = -__expf(a0.y); Av[2] = -__expf(a0.z); Av[3] = -__expf(a0.w);
        Av[4] = -__expf(a1.x); Av[5] = -__expf(a1.y); Av[6] = -__expf(a1.z); Av[7] = -__expf(a1.w);
    }

    float s[8];
#pragma unroll
    for (int n = 0; n < 8; n++) s[n] = 0.f;
    float sumdv = 0.f;
    const int t0 = w * 16;
    __syncthreads();

    // phase 1: local segment scan (s_in = 0)
#pragma unroll 4
    for (int tt = 0; tt < 16; tt++) {
        int t = t0 + tt;
        size_t idx = (size_t)(mbase + t) * 2048 + d;
        float dvv = delta[idx];
        float uv  = bf2f(ub[idx]);
        float dvu = dvv * uv;
        sumdv += dvv;
        const float* Brow = &Bsh[t * 16 + h * 8];
#pragma unroll
        for (int n = 0; n < 8; n++) {
            float dA = __expf(dvv * Av[n]);
            s[n] = fmaf(dA, s[n], dvu * Brow[n]);
        }
    }
#pragma unroll
    for (int n = 0; n < 8; n++) sQ[w][dl][h * 8 + n] = s[n];
    if (h == 0) sS[w][dl] = sumdv;
    __syncthreads();

    // phase 2: compose carry from lower segments
    {
        float sin_[8];
#pragma unroll
        for (int n = 0; n < 8; n++) sin_[n] = 0.f;
        float cc = 0.f;
        for (int v = w - 1; v >= 0; v--) {
#pragma unroll
            for (int n = 0; n < 8; n++)
                sin_[n] += __expf(Av[n] * cc) * sQ[v][dl][h * 8 + n];
            cc += sS[v][dl];
        }
#pragma unroll
        for (int n = 0; n < 8; n++) s[n] = sin_[n];
    }

    // phase 3: replay with carry (delta/ub reload is L2-hot), emit gated y
#pragma unroll 2
    for (int tt = 0; tt < 16; tt++) {
        int t = t0 + tt;
        size_t idx = (size_t)(mbase + t) * 2048 + d;
        float dvv = delta[idx];
        float uv  = bf2f(ub[idx]);
        float dvu = dvv * uv;
        const float* Brow = &Bsh[t * 16 + h * 8];
        const float* Crow = &Csh[t * 16 + h * 8];
        float y = 0.f;
#pragma unroll
        for (int n = 0; n < 8; n++) {
            float dA = __expf(dvv * Av[n]);
            s[n] = fmaf(dA, s[n], dvu * Brow[n]);
            y = fmaf(s[n], Crow[n], y);
        }
        y += __shfl_xor(y, 32);
        if (h == 0) {
            float sr = bf2f(sgb[idx]);
            ygb[idx] = f2bf(y * sr);
        }
    }
}

extern "C" void kernel_launch(void* const* d_in, const int* in_sizes, int n_in,
                              void* d_out, int out_size, void* d_ws, size_t ws_size,
                              hipStream_t stream)
{
    const float* x      = (const float*)d_in[0];   // (2,1024,1024) fp32
    const float* W_in   = (const float*)d_in[1];   // (4096,1024)
    const float* b_in   = (const float*)d_in[2];   // (4096,)
    const float* conv_w = (const float*)d_in[3];   // (2048,1,3)
    const float* conv_b = (const float*)d_in[4];   // (2048,)
    const float* W_x    = (const float*)d_in[5];   // (96,2048)
    const float* W_dt   = (const float*)d_in[6];   // (2048,64)
    const float* b_dt   = (const float*)d_in[7];   // (2048,)
    const float* A_log  = (const float*)d_in[8];   // (2048,16)
    const float* W_out  = (const float*)d_in[9];   // (1024,2048)
    const float* b_out  = (const float*)d_in[10];  // (1024,)
    float* out = (float*)d_out;                    // (2,1024,1024) fp32

    // Workspace ~72.3 MB, NO ALIASING (r13 post-mortem: output depended on
    // initial d_ws contents via the xcb/delta alias; every buffer now has
    // exactly one role).
    char* p = (char*)d_ws;
    auto alloc = [&](size_t bytes) { char* r = p; p += (bytes + 255) & ~(size_t)255; return r; };
    ushort_t* xbf    = (ushort_t*)alloc(2048ull * 1024 * 2);   // 4 MB
    ushort_t* winbf  = (ushort_t*)alloc(4096ull * 1024 * 2);   // 8 MB
    ushort_t* wxbf   = (ushort_t*)alloc(96ull * 2048 * 2);
    ushort_t* wdtbf  = (ushort_t*)alloc(2048ull * 64 * 2);
    ushort_t* woutbf = (ushort_t*)alloc(1024ull * 2048 * 2);   // 4 MB
    ushort_t* xcb    = (ushort_t*)alloc(2048ull * 2048 * 2);   // 8 MB  conv input
    float*    delta  = (float*)alloc(2048ull * 2048 * 4);      // 16 MB
    ushort_t* sgb    = (ushort_t*)alloc(2048ull * 2048 * 2);   // 8 MB  silu(res)
    ushort_t* ub     = (ushort_t*)alloc(2048ull * 2048 * 2);   // 8 MB
    float*    xpp    = (float*)alloc(8ull * 2048 * 96 * 4);    // 6.3 MB (split-K=8)
    float*    xp     = (float*)alloc(2048ull * 96 * 4);
    ushort_t* dltb   = (ushort_t*)alloc(2048ull * 64 * 2);
    ushort_t* ygb    = (ushort_t*)alloc(2048ull * 2048 * 2);   // 8 MB

    // 0. round x + weights to bf16
    cvt5<<<8512, 256, 0, stream>>>(x, W_in, W_x, W_dt, W_out,
                                   xbf, winbf, wxbf, wdtbf, woutbf);

    // 1. in_proj: xr = x @ W_in^T + b_in -> xc bf16 | silu(res) bf16.
    //    128x64 tiles -> grid (16,64) = 1024 blocks = 4 blocks/CU (16 waves/CU)
    //    vs r15's 128x128 at 512 blocks = 2/CU (8 waves/CU, latency-exposed).
    gemm_bt<128, 64, 64, 2, 2, EPI_SPLIT><<<dim3(16, 64), 256, 0, stream>>>(
        xbf, 1024, winbf, 1024, nullptr, sgb, xcb, b_in, 4096, 1024);

    // 2. depthwise causal conv + silu -> ub (bf16)
    conv_silu<<<4096, 256, 0, stream>>>(xcb, conv_w, conv_b, ub);

    // 3. x_proj: xp = u @ W_x^T.  32x96 tiles, split-K=8 -> 512 blocks (2/CU)
    gemm_bt<32, 96, 64, 2, 2, EPI_PARTIAL><<<dim3(64, 1, 8), 256, 0, stream>>>(
        ub, 2048, wxbf, 2048, xpp, nullptr, nullptr, nullptr, 96, 256);

    // 4. reduce partials -> xp fp32, dlt bf16
    xp_reduce<<<768, 256, 0, stream>>>(xpp, xp, dltb);

    // 5. dt_proj: delta = softplus(dlt @ W_dt^T + b_dt) (fp32)
    gemm_bt<64, 64, 64, 2, 2, EPI_SOFTPLUS><<<dim3(32, 32), 256, 0, stream>>>(
        dltb, 64, wdtbf, 64, delta, nullptr, nullptr, b_dt, 2048, 64);

    // 6. two-pass wave-parallel chunked scan + gate -> ygb (bf16)
    scan_kernel<<<dim3(64, 8), 1024, 0, stream>>>(delta, ub, xp, A_log, sgb, ygb);

    // 7. out_proj: out = yg @ W_out^T + b_out (fp32).  BK=128 halves the
    //    K-loop to 16 iterations (half the barrier drains); LDS 32 KB.
    gemm_bt<64, 64, 128, 2, 2, EPI_OUT><<<dim3(32, 16), 256, 0, stream>>>(
        ygb, 2048, woutbf, 2048, out, nullptr, nullptr, b_out, 1024, 2048);
}

// Round 17
// 218.079 us; speedup vs baseline: 1.0278x; 1.0278x over previous
//
#include <hip/hip_runtime.h>
#include <stdint.h>
#include <stddef.h>

typedef __attribute__((ext_vector_type(8))) short short8;
typedef __attribute__((ext_vector_type(4))) float floatx4;
typedef unsigned short ushort_t;

__device__ __forceinline__ ushort_t f2bf(float f) {
    union { float f; uint32_t u; } v; v.f = f;
    return (ushort_t)((v.u + 0x7fffu + ((v.u >> 16) & 1u)) >> 16);
}
__device__ __forceinline__ float bf2f(ushort_t u) {
    union { uint32_t u; float f; } v; v.u = ((uint32_t)u) << 16; return v.f;
}

// async global->LDS 16B staging (m97). LDS dest = wave-uniform base + lane*16.
__device__ __forceinline__ void load16_lds(const ushort_t* g, short* l) {
    __builtin_amdgcn_global_load_lds((const __attribute__((address_space(1))) void*)g,
                                     (__attribute__((address_space(3))) void*)l, 16, 0, 0);
}

enum { EPI_SPLIT = 0, EPI_SOFTPLUS = 1, EPI_OUT = 2, EPI_PARTIAL = 3 };

// Convert x + 4 weights fp32 -> bf16 in one launch.
__global__ __launch_bounds__(256)
void cvt5(const float* __restrict__ x, const float* __restrict__ win,
          const float* __restrict__ wx, const float* __restrict__ wdt,
          const float* __restrict__ wout,
          ushort_t* __restrict__ xb, ushort_t* __restrict__ winb,
          ushort_t* __restrict__ wxb, ushort_t* __restrict__ wdtb,
          ushort_t* __restrict__ woutb)
{
    int g = blockIdx.x * 256 + threadIdx.x;   // < 2179072 exactly
    const float* s; ushort_t* d; int off;
    if      (g < 524288)  { s = x;    d = xb;    off = g; }
    else if (g < 1572864) { s = win;  d = winb;  off = g - 524288; }
    else if (g < 1622016) { s = wx;   d = wxb;   off = g - 1572864; }
    else if (g < 1654784) { s = wdt;  d = wdtb;  off = g - 1622016; }
    else                  { s = wout; d = woutb; off = g - 1654784; }
    float4 v = reinterpret_cast<const float4*>(s)[off];
    union { ushort_t u[4]; uint2 q; } o;
    o.u[0] = f2bf(v.x); o.u[1] = f2bf(v.y); o.u[2] = f2bf(v.z); o.u[3] = f2bf(v.w);
    *reinterpret_cast<uint2*>(d + (size_t)off * 4) = o.q;
}

// C[m,n] = sum_k A[m,k] * B[n,k]  (bf16 operands, fp32 accum)
template<int BM, int BN, int BK, int WR, int WC, int EPI>
__global__ __launch_bounds__(256)
void gemm_bt(const ushort_t* __restrict__ A, int lda,
             const ushort_t* __restrict__ Bw, int ldb,
             float* __restrict__ out0,
             ushort_t* __restrict__ outg,   // EPI_SPLIT gate half (silu bf16)
             ushort_t* __restrict__ outc,   // EPI_SPLIT conv half (bf16)
             const float* __restrict__ bias,
             int N, int kchunk)
{
    constexpr int TM = BM / WR / 16;
    constexpr int TN = BN / WC / 16;
    static_assert(BM % (WR * 16) == 0 && BN % (WC * 16) == 0, "tile");
    static_assert((BM * BK) % 2048 == 0 && (BN * BK) % 2048 == 0, "stage");

    __shared__ __align__(16) short As[BM * BK];
    __shared__ __align__(16) short Bs[BN * BK];

    const int tid  = threadIdx.x;
    const int m0   = blockIdx.x * BM;
    const int n0   = blockIdx.y * BN;
    const int ks   = blockIdx.z;
    const int kbeg = ks * kchunk;

    const int w    = tid >> 6;
    const int lane = tid & 63;
    const int quad = lane >> 4;
    const int l16  = lane & 15;
    const int wr   = w / WC, wc = w % WC;
    const int wm   = wr * (BM / WR);
    const int wn   = wc * (BN / WC);

    floatx4 acc[TM][TN];
#pragma unroll
    for (int i = 0; i < TM; i++)
#pragma unroll
        for (int j = 0; j < TN; j++) acc[i][j] = (floatx4){0.f, 0.f, 0.f, 0.f};

    constexpr int nA = BM * BK / 2048;
    constexpr int nB = BN * BK / 2048;
    constexpr int CPR = BK / 8;

    for (int kb = kbeg; kb < kbeg + kchunk; kb += BK) {
        __syncthreads();
#pragma unroll
        for (int i = 0; i < nA; i++) {
            int c = i * 256 + tid;
            int r = c / CPR, kc = (c % CPR) * 8;
            load16_lds(A + (size_t)(m0 + r) * lda + kb + kc, &As[r * BK + kc]);
        }
#pragma unroll
        for (int i = 0; i < nB; i++) {
            int c = i * 256 + tid;
            int r = c / CPR, kc = (c % CPR) * 8;
            load16_lds(Bw + (size_t)(n0 + r) * ldb + kb + kc, &Bs[r * BK + kc]);
        }
        __syncthreads();
#pragma unroll
        for (int kk = 0; kk < BK / 32; kk++) {
            short8 af[TM], bfr[TN];
#pragma unroll
            for (int t = 0; t < TM; t++)
                af[t] = *reinterpret_cast<const short8*>(&As[(wm + t * 16 + l16) * BK + kk * 32 + quad * 8]);
#pragma unroll
            for (int u2 = 0; u2 < TN; u2++)
                bfr[u2] = *reinterpret_cast<const short8*>(&Bs[(wn + u2 * 16 + l16) * BK + kk * 32 + quad * 8]);
#pragma unroll
            for (int t = 0; t < TM; t++)
#pragma unroll
                for (int u2 = 0; u2 < TN; u2++)
                    acc[t][u2] = __builtin_amdgcn_mfma_f32_16x16x32_bf16(af[t], bfr[u2], acc[t][u2], 0, 0, 0);
        }
    }

#pragma unroll
    for (int t = 0; t < TM; t++) {
#pragma unroll
        for (int u2 = 0; u2 < TN; u2++) {
#pragma unroll
            for (int r = 0; r < 4; r++) {
                int row = m0 + wm + t * 16 + quad * 4 + r;
                int col = n0 + wn + u2 * 16 + l16;
                float val = acc[t][u2][r];
                if (EPI == EPI_SPLIT) {
                    val += bias[col];
                    if (col < 2048) {
                        outc[(size_t)row * 2048 + col] = f2bf(val);
                    } else {
                        float sr = val / (1.f + __expf(-val));
                        outg[(size_t)row * 2048 + col - 2048] = f2bf(sr);
                    }
                } else if (EPI == EPI_SOFTPLUS) {
                    val += bias[col];
                    float sp = fmaxf(val, 0.f) + __logf(1.f + __expf(-fabsf(val)));
                    out0[(size_t)row * N + col] = sp;
                } else if (EPI == EPI_OUT) {
                    val += bias[col];
                    out0[(size_t)row * N + col] = val;
                } else { // EPI_PARTIAL: split-K partials [ks][m][96]
                    out0[((size_t)ks * 2048 + row) * 96 + col] = val;
                }
            }
        }
    }
}

// depthwise causal conv (k=3) + silu. bf16 in, bf16 out.
__global__ __launch_bounds__(256)
void conv_silu(const ushort_t* __restrict__ xc, const float* __restrict__ cw,
               const float* __restrict__ cb, ushort_t* __restrict__ ub)
{
    int id = blockIdx.x * 256 + threadIdx.x;   // 2048 * 512
    int m  = id >> 9;
    int d4 = (id & 511) * 4;
    int l  = m & 1023;

    union { uint2 q; ushort_t u[4]; } a, b, c;
    a.q = *reinterpret_cast<const uint2*>(xc + (size_t)m * 2048 + d4);
    if (l >= 1) b.q = *reinterpret_cast<const uint2*>(xc + (size_t)(m - 1) * 2048 + d4);
    else        { b.q.x = 0; b.q.y = 0; }
    if (l >= 2) c.q = *reinterpret_cast<const uint2*>(xc + (size_t)(m - 2) * 2048 + d4);
    else        { c.q.x = 0; c.q.y = 0; }

    union { ushort_t u[4]; uint2 q; } o;
#pragma unroll
    for (int j = 0; j < 4; j++) {
        int d = d4 + j;
        float v = cb[d] + cw[d * 3 + 0] * bf2f(c.u[j]) + cw[d * 3 + 1] * bf2f(b.u[j])
                        + cw[d * 3 + 2] * bf2f(a.u[j]);
        o.u[j] = f2bf(v / (1.f + __expf(-v)));
    }
    *reinterpret_cast<uint2*>(ub + (size_t)m * 2048 + d4) = o.q;
}

// reduce split-K=8 partials -> xp fp32 (2048 x 96) and dlt bf16 (2048 x 64)
__global__ __launch_bounds__(256)
void xp_reduce(const float* __restrict__ part, float* __restrict__ xp, ushort_t* __restrict__ dltb)
{
    int e = blockIdx.x * 256 + threadIdx.x;    // < 2048*96 exactly
    float s = 0.f;
#pragma unroll
    for (int ks = 0; ks < 8; ks++) s += part[(size_t)ks * 2048 * 96 + e];
    xp[e] = s;
    int n = e % 96, m = e / 96;
    if (n < 64) dltb[(size_t)m * 64 + n] = f2bf(s);
}

// Chunked selective scan — two-pass structure (28 VGPRs measured, 44.8 us,
// zero bank conflicts). DO NOT add phase-crossing register arrays (r10/r11/
// r12 all spilled to scratch, 8-30x slowdowns).
// Block = 1024 thr = 16 waves, one 256-token chunk x 32 channels.
// lane&31 = channel, lane>>5 = state-half h. Wave w owns t in [16w,16w+16).
__global__ __launch_bounds__(1024, 8)
void scan_kernel(const float* __restrict__ delta, const ushort_t* __restrict__ ub,
                 const float* __restrict__ xp, const float* __restrict__ A_log,
                 const ushort_t* __restrict__ sgb, ushort_t* __restrict__ ygb)
{
    __shared__ __align__(16) float Bsh[256 * 16];
    __shared__ __align__(16) float Csh[256 * 16];
    __shared__ float sQ[16][32][17];
    __shared__ float sS[16][32];

    const int tid  = threadIdx.x;
    const int w    = tid >> 6;                // wave = time segment
    const int lane = tid & 63;
    const int dl   = lane & 31;               // channel within tile
    const int h    = lane >> 5;               // state half
    const int d    = blockIdx.x * 32 + dl;
    const int c    = blockIdx.y;              // (batch<<2)|chunk
    const int mbase = (c >> 2) * 1024 + (c & 3) * 256;

    {   // stage B (xp cols 64..79) / C (80..95): 4 threads per row
        int r = tid >> 2, part = tid & 3;
        const float4* rp = reinterpret_cast<const float4*>(xp + (size_t)(mbase + r) * 96 + 64);
        reinterpret_cast<float4*>(Bsh + r * 16)[part] = rp[part];
        reinterpret_cast<float4*>(Csh + r * 16)[part] = rp[part + 4];
    }

    float Av[8];
    {
        const float4* ap = reinterpret_cast<const float4*>(A_log + (size_t)d * 16 + h * 8);
        float4 a0 = ap[0], a1 = ap[1];
        Av[0] = -__expf(a0.x); Av[1] = -__expf(a0.y); Av[2] = -__expf(a0.z); Av[3] = -__expf(a0.w);
        Av[4] = -__expf(a1.x); Av[5] = -__expf(a1.y); Av[6] = -__expf(a1.z); Av[7] = -__expf(a1.w);
    }

    float s[8];
#pragma unroll
    for (int n = 0; n < 8; n++) s[n] = 0.f;
    float sumdv = 0.f;
    const int t0 = w * 16;
    __syncthreads();

    // phase 1: local segment scan (s_in = 0)
#pragma unroll 4
    for (int tt = 0; tt < 16; tt++) {
        int t = t0 + tt;
        size_t idx = (size_t)(mbase + t) * 2048 + d;
        float dvv = delta[idx];
        float uv  = bf2f(ub[idx]);
        float dvu = dvv * uv;
        sumdv += dvv;
        const float* Brow = &Bsh[t * 16 + h * 8];
#pragma unroll
        for (int n = 0; n < 8; n++) {
            float dA = __expf(dvv * Av[n]);
            s[n] = fmaf(dA, s[n], dvu * Brow[n]);
        }
    }
#pragma unroll
    for (int n = 0; n < 8; n++) sQ[w][dl][h * 8 + n] = s[n];
    if (h == 0) sS[w][dl] = sumdv;
    __syncthreads();

    // phase 2: compose carry from lower segments
    {
        float sin_[8];
#pragma unroll
        for (int n = 0; n < 8; n++) sin_[n] = 0.f;
        float cc = 0.f;
        for (int v = w - 1; v >= 0; v--) {
#pragma unroll
            for (int n = 0; n < 8; n++)
                sin_[n] += __expf(Av[n] * cc) * sQ[v][dl][h * 8 + n];
            cc += sS[v][dl];
        }
#pragma unroll
        for (int n = 0; n < 8; n++) s[n] = sin_[n];
    }

    // phase 3: replay with carry (delta/ub reload is L2-hot), emit gated y
#pragma unroll 2
    for (int tt = 0; tt < 16; tt++) {
        int t = t0 + tt;
        size_t idx = (size_t)(mbase + t) * 2048 + d;
        float dvv = delta[idx];
        float uv  = bf2f(ub[idx]);
        float dvu = dvv * uv;
        const float* Brow = &Bsh[t * 16 + h * 8];
        const float* Crow = &Csh[t * 16 + h * 8];
        float y = 0.f;
#pragma unroll
        for (int n = 0; n < 8; n++) {
            float dA = __expf(dvv * Av[n]);
            s[n] = fmaf(dA, s[n], dvu * Brow[n]);
            y = fmaf(s[n], Crow[n], y);
        }
        y += __shfl_xor(y, 32);
        if (h == 0) {
            float sr = bf2f(sgb[idx]);
            ygb[idx] = f2bf(y * sr);
        }
    }
}

extern "C" void kernel_launch(void* const* d_in, const int* in_sizes, int n_in,
                              void* d_out, int out_size, void* d_ws, size_t ws_size,
                              hipStream_t stream)
{
    const float* x      = (const float*)d_in[0];   // (2,1024,1024) fp32
    const float* W_in   = (const float*)d_in[1];   // (4096,1024)
    const float* b_in   = (const float*)d_in[2];   // (4096,)
    const float* conv_w = (const float*)d_in[3];   // (2048,1,3)
    const float* conv_b = (const float*)d_in[4];   // (2048,)
    const float* W_x    = (const float*)d_in[5];   // (96,2048)
    const float* W_dt   = (const float*)d_in[6];   // (2048,64)
    const float* b_dt   = (const float*)d_in[7];   // (2048,)
    const float* A_log  = (const float*)d_in[8];   // (2048,16)
    const float* W_out  = (const float*)d_in[9];   // (1024,2048)
    const float* b_out  = (const float*)d_in[10];  // (1024,)
    float* out = (float*)d_out;                    // (2,1024,1024) fp32

    // Workspace ~72.3 MB, NO ALIASING (r13 post-mortem: output depended on
    // initial d_ws contents via the xcb/delta alias; every buffer now has
    // exactly one role).
    char* p = (char*)d_ws;
    auto alloc = [&](size_t bytes) { char* r = p; p += (bytes + 255) & ~(size_t)255; return r; };
    ushort_t* xbf    = (ushort_t*)alloc(2048ull * 1024 * 2);   // 4 MB
    ushort_t* winbf  = (ushort_t*)alloc(4096ull * 1024 * 2);   // 8 MB
    ushort_t* wxbf   = (ushort_t*)alloc(96ull * 2048 * 2);
    ushort_t* wdtbf  = (ushort_t*)alloc(2048ull * 64 * 2);
    ushort_t* woutbf = (ushort_t*)alloc(1024ull * 2048 * 2);   // 4 MB
    ushort_t* xcb    = (ushort_t*)alloc(2048ull * 2048 * 2);   // 8 MB  conv input
    float*    delta  = (float*)alloc(2048ull * 2048 * 4);      // 16 MB
    ushort_t* sgb    = (ushort_t*)alloc(2048ull * 2048 * 2);   // 8 MB  silu(res)
    ushort_t* ub     = (ushort_t*)alloc(2048ull * 2048 * 2);   // 8 MB
    float*    xpp    = (float*)alloc(8ull * 2048 * 96 * 4);    // 6.3 MB (split-K=8)
    float*    xp     = (float*)alloc(2048ull * 96 * 4);
    ushort_t* dltb   = (ushort_t*)alloc(2048ull * 64 * 2);
    ushort_t* ygb    = (ushort_t*)alloc(2048ull * 2048 * 2);   // 8 MB

    // 0. round x + weights to bf16
    cvt5<<<8512, 256, 0, stream>>>(x, W_in, W_x, W_dt, W_out,
                                   xbf, winbf, wxbf, wdtbf, woutbf);

    // 1. in_proj: xr = x @ W_in^T + b_in -> xc bf16 | silu(res) bf16.
    //    128x128 tiles, grid (16,32) — r16 showed 128x64 (more blocks but 2x
    //    A-staging traffic) REGRESSES: compute:staging ratio beats occupancy.
    gemm_bt<128, 128, 64, 2, 2, EPI_SPLIT><<<dim3(16, 32), 256, 0, stream>>>(
        xbf, 1024, winbf, 1024, nullptr, sgb, xcb, b_in, 4096, 1024);

    // 2. depthwise causal conv + silu -> ub (bf16)
    conv_silu<<<4096, 256, 0, stream>>>(xcb, conv_w, conv_b, ub);

    // 3. x_proj: xp = u @ W_x^T.  32x96 tiles, split-K=8 -> 512 blocks (2/CU)
    gemm_bt<32, 96, 64, 2, 2, EPI_PARTIAL><<<dim3(64, 1, 8), 256, 0, stream>>>(
        ub, 2048, wxbf, 2048, xpp, nullptr, nullptr, nullptr, 96, 256);

    // 4. reduce partials -> xp fp32, dlt bf16
    xp_reduce<<<768, 256, 0, stream>>>(xpp, xp, dltb);

    // 5. dt_proj: delta = softplus(dlt @ W_dt^T + b_dt) (fp32)
    gemm_bt<64, 64, 64, 2, 2, EPI_SOFTPLUS><<<dim3(32, 32), 256, 0, stream>>>(
        dltb, 64, wdtbf, 64, delta, nullptr, nullptr, b_dt, 2048, 64);

    // 6. two-pass wave-parallel chunked scan + gate -> ygb (bf16)
    scan_kernel<<<dim3(64, 8), 1024, 0, stream>>>(delta, ub, xp, A_log, sgb, ygb);

    // 7. out_proj: out = yg @ W_out^T + b_out (fp32).  BK=64 (r16's BK=128
    //    was part of a net regression), 64x64 tiles -> 512 blocks.
    gemm_bt<64, 64, 64, 2, 2, EPI_OUT><<<dim3(32, 16), 256, 0, stream>>>(
        ygb, 2048, woutbf, 2048, out, nullptr, nullptr, b_out, 1024, 2048);
}

// Round 18
// 211.145 us; speedup vs baseline: 1.0616x; 1.0328x over previous
//
#include <hip/hip_runtime.h>
#include <stdint.h>
#include <stddef.h>

typedef __attribute__((ext_vector_type(8))) short short8;
typedef __attribute__((ext_vector_type(4))) float floatx4;
typedef unsigned short ushort_t;

__device__ __forceinline__ ushort_t f2bf(float f) {
    union { float f; uint32_t u; } v; v.f = f;
    return (ushort_t)((v.u + 0x7fffu + ((v.u >> 16) & 1u)) >> 16);
}
__device__ __forceinline__ float bf2f(ushort_t u) {
    union { uint32_t u; float f; } v; v.u = ((uint32_t)u) << 16; return v.f;
}

// async global->LDS 16B staging (m97). LDS dest = wave-uniform base + lane*16.
__device__ __forceinline__ void load16_lds(const ushort_t* g, short* l) {
    __builtin_amdgcn_global_load_lds((const __attribute__((address_space(1))) void*)g,
                                     (__attribute__((address_space(3))) void*)l, 16, 0, 0);
}

enum { EPI_SPLIT = 0, EPI_SOFTPLUS = 1, EPI_OUT = 2, EPI_PARTIAL = 3 };

// Convert x + 4 weights fp32 -> bf16 in one launch.
__global__ __launch_bounds__(256)
void cvt5(const float* __restrict__ x, const float* __restrict__ win,
          const float* __restrict__ wx, const float* __restrict__ wdt,
          const float* __restrict__ wout,
          ushort_t* __restrict__ xb, ushort_t* __restrict__ winb,
          ushort_t* __restrict__ wxb, ushort_t* __restrict__ wdtb,
          ushort_t* __restrict__ woutb)
{
    int g = blockIdx.x * 256 + threadIdx.x;   // < 2179072 exactly
    const float* s; ushort_t* d; int off;
    if      (g < 524288)  { s = x;    d = xb;    off = g; }
    else if (g < 1572864) { s = win;  d = winb;  off = g - 524288; }
    else if (g < 1622016) { s = wx;   d = wxb;   off = g - 1572864; }
    else if (g < 1654784) { s = wdt;  d = wdtb;  off = g - 1622016; }
    else                  { s = wout; d = woutb; off = g - 1654784; }
    float4 v = reinterpret_cast<const float4*>(s)[off];
    union { ushort_t u[4]; uint2 q; } o;
    o.u[0] = f2bf(v.x); o.u[1] = f2bf(v.y); o.u[2] = f2bf(v.z); o.u[3] = f2bf(v.w);
    *reinterpret_cast<uint2*>(d + (size_t)off * 4) = o.q;
}

// C[m,n] = sum_k A[m,k] * B[n,k]  (bf16 operands, fp32 accum)
// LDS BANK-CONFLICT FIX (r17): row stride BK=64 shorts = 128 B == 0 mod 32
// banks, so all 16 lanes of a quad (same k, rows 16 apart) hit the same 4
// banks -> 16-way conflict (6.3M stall cycles on in_proj). Padding is
// impossible (global_load_lds needs tid-contiguous LDS dests), so we XOR-
// swizzle the chunk->column mapping: LDS slot (r,j) holds global chunk
// (r, j^(r&7)). Write side stays contiguous; each row's 8 chunks still map
// to the same contiguous 128 B of global memory (coalescing unchanged);
// read side uses j = kcc^(row&7) -> quad lanes span all 32 banks, 2-way
// (free per m136). Pure permutation: bit-identical results.
template<int BM, int BN, int BK, int WR, int WC, int EPI>
__global__ __launch_bounds__(256)
void gemm_bt(const ushort_t* __restrict__ A, int lda,
             const ushort_t* __restrict__ Bw, int ldb,
             float* __restrict__ out0,
             ushort_t* __restrict__ outg,   // EPI_SPLIT gate half (silu bf16)
             ushort_t* __restrict__ outc,   // EPI_SPLIT conv half (bf16)
             const float* __restrict__ bias,
             int N, int kchunk)
{
    constexpr int TM = BM / WR / 16;
    constexpr int TN = BN / WC / 16;
    static_assert(BM % (WR * 16) == 0 && BN % (WC * 16) == 0, "tile");
    static_assert((BM * BK) % 2048 == 0 && (BN * BK) % 2048 == 0, "stage");
    static_assert(BK == 64, "swizzle assumes CPR=8");

    __shared__ __align__(16) short As[BM * BK];
    __shared__ __align__(16) short Bs[BN * BK];

    const int tid  = threadIdx.x;
    const int m0   = blockIdx.x * BM;
    const int n0   = blockIdx.y * BN;
    const int ks   = blockIdx.z;
    const int kbeg = ks * kchunk;

    const int w    = tid >> 6;
    const int lane = tid & 63;
    const int quad = lane >> 4;
    const int l16  = lane & 15;
    const int wr   = w / WC, wc = w % WC;
    const int wm   = wr * (BM / WR);
    const int wn   = wc * (BN / WC);

    floatx4 acc[TM][TN];
#pragma unroll
    for (int i = 0; i < TM; i++)
#pragma unroll
        for (int j = 0; j < TN; j++) acc[i][j] = (floatx4){0.f, 0.f, 0.f, 0.f};

    constexpr int nA = BM * BK / 2048;
    constexpr int nB = BN * BK / 2048;
    constexpr int CPR = BK / 8;

    for (int kb = kbeg; kb < kbeg + kchunk; kb += BK) {
        __syncthreads();
#pragma unroll
        for (int i = 0; i < nA; i++) {
            int c = i * 256 + tid;
            int r = c / CPR, j = c % CPR;
            int kg = (j ^ (r & 7)) * 8;          // swizzled source column
            load16_lds(A + (size_t)(m0 + r) * lda + kb + kg, &As[c * 8]);
        }
#pragma unroll
        for (int i = 0; i < nB; i++) {
            int c = i * 256 + tid;
            int r = c / CPR, j = c % CPR;
            int kg = (j ^ (r & 7)) * 8;
            load16_lds(Bw + (size_t)(n0 + r) * ldb + kb + kg, &Bs[c * 8]);
        }
        __syncthreads();
#pragma unroll
        for (int kk = 0; kk < BK / 32; kk++) {
            short8 af[TM], bfr[TN];
#pragma unroll
            for (int t = 0; t < TM; t++) {
                int row = wm + t * 16 + l16;
                int kcc = kk * 4 + quad;
                af[t] = *reinterpret_cast<const short8*>(&As[row * BK + ((kcc ^ (row & 7)) * 8)]);
            }
#pragma unroll
            for (int u2 = 0; u2 < TN; u2++) {
                int row = wn + u2 * 16 + l16;
                int kcc = kk * 4 + quad;
                bfr[u2] = *reinterpret_cast<const short8*>(&Bs[row * BK + ((kcc ^ (row & 7)) * 8)]);
            }
#pragma unroll
            for (int t = 0; t < TM; t++)
#pragma unroll
                for (int u2 = 0; u2 < TN; u2++)
                    acc[t][u2] = __builtin_amdgcn_mfma_f32_16x16x32_bf16(af[t], bfr[u2], acc[t][u2], 0, 0, 0);
        }
    }

#pragma unroll
    for (int t = 0; t < TM; t++) {
#pragma unroll
        for (int u2 = 0; u2 < TN; u2++) {
#pragma unroll
            for (int r = 0; r < 4; r++) {
                int row = m0 + wm + t * 16 + quad * 4 + r;
                int col = n0 + wn + u2 * 16 + l16;
                float val = acc[t][u2][r];
                if (EPI == EPI_SPLIT) {
                    val += bias[col];
                    if (col < 2048) {
                        outc[(size_t)row * 2048 + col] = f2bf(val);
                    } else {
                        float sr = val / (1.f + __expf(-val));
                        outg[(size_t)row * 2048 + col - 2048] = f2bf(sr);
                    }
                } else if (EPI == EPI_SOFTPLUS) {
                    val += bias[col];
                    float sp = fmaxf(val, 0.f) + __logf(1.f + __expf(-fabsf(val)));
                    out0[(size_t)row * N + col] = sp;
                } else if (EPI == EPI_OUT) {
                    val += bias[col];
                    out0[(size_t)row * N + col] = val;
                } else { // EPI_PARTIAL: split-K partials [ks][m][96]
                    out0[((size_t)ks * 2048 + row) * 96 + col] = val;
                }
            }
        }
    }
}

// depthwise causal conv (k=3) + silu. bf16 in, bf16 out.
__global__ __launch_bounds__(256)
void conv_silu(const ushort_t* __restrict__ xc, const float* __restrict__ cw,
               const float* __restrict__ cb, ushort_t* __restrict__ ub)
{
    int id = blockIdx.x * 256 + threadIdx.x;   // 2048 * 512
    int m  = id >> 9;
    int d4 = (id & 511) * 4;
    int l  = m & 1023;

    union { uint2 q; ushort_t u[4]; } a, b, c;
    a.q = *reinterpret_cast<const uint2*>(xc + (size_t)m * 2048 + d4);
    if (l >= 1) b.q = *reinterpret_cast<const uint2*>(xc + (size_t)(m - 1) * 2048 + d4);
    else        { b.q.x = 0; b.q.y = 0; }
    if (l >= 2) c.q = *reinterpret_cast<const uint2*>(xc + (size_t)(m - 2) * 2048 + d4);
    else        { c.q.x = 0; c.q.y = 0; }

    union { ushort_t u[4]; uint2 q; } o;
#pragma unroll
    for (int j = 0; j < 4; j++) {
        int d = d4 + j;
        float v = cb[d] + cw[d * 3 + 0] * bf2f(c.u[j]) + cw[d * 3 + 1] * bf2f(b.u[j])
                        + cw[d * 3 + 2] * bf2f(a.u[j]);
        o.u[j] = f2bf(v / (1.f + __expf(-v)));
    }
    *reinterpret_cast<uint2*>(ub + (size_t)m * 2048 + d4) = o.q;
}

// reduce split-K=8 partials -> xp fp32 (2048 x 96) and dlt bf16 (2048 x 64)
__global__ __launch_bounds__(256)
void xp_reduce(const float* __restrict__ part, float* __restrict__ xp, ushort_t* __restrict__ dltb)
{
    int e = blockIdx.x * 256 + threadIdx.x;    // < 2048*96 exactly
    float s = 0.f;
#pragma unroll
    for (int ks = 0; ks < 8; ks++) s += part[(size_t)ks * 2048 * 96 + e];
    xp[e] = s;
    int n = e % 96, m = e / 96;
    if (n < 64) dltb[(size_t)m * 64 + n] = f2bf(s);
}

// Chunked selective scan — two-pass structure (28 VGPRs measured, 44.8 us,
// zero bank conflicts). DO NOT add phase-crossing register arrays (r10/r11/
// r12 all spilled to scratch, 8-30x slowdowns).
// Block = 1024 thr = 16 waves, one 256-token chunk x 32 channels.
// lane&31 = channel, lane>>5 = state-half h. Wave w owns t in [16w,16w+16).
__global__ __launch_bounds__(1024, 8)
void scan_kernel(const float* __restrict__ delta, const ushort_t* __restrict__ ub,
                 const float* __restrict__ xp, const float* __restrict__ A_log,
                 const ushort_t* __restrict__ sgb, ushort_t* __restrict__ ygb)
{
    __shared__ __align__(16) float Bsh[256 * 16];
    __shared__ __align__(16) float Csh[256 * 16];
    __shared__ float sQ[16][32][17];
    __shared__ float sS[16][32];

    const int tid  = threadIdx.x;
    const int w    = tid >> 6;                // wave = time segment
    const int lane = tid & 63;
    const int dl   = lane & 31;               // channel within tile
    const int h    = lane >> 5;               // state half
    const int d    = blockIdx.x * 32 + dl;
    const int c    = blockIdx.y;              // (batch<<2)|chunk
    const int mbase = (c >> 2) * 1024 + (c & 3) * 256;

    {   // stage B (xp cols 64..79) / C (80..95): 4 threads per row
        int r = tid >> 2, part = tid & 3;
        const float4* rp = reinterpret_cast<const float4*>(xp + (size_t)(mbase + r) * 96 + 64);
        reinterpret_cast<float4*>(Bsh + r * 16)[part] = rp[part];
        reinterpret_cast<float4*>(Csh + r * 16)[part] = rp[part + 4];
    }

    float Av[8];
    {
        const float4* ap = reinterpret_cast<const float4*>(A_log + (size_t)d * 16 + h * 8);
        float4 a0 = ap[0], a1 = ap[1];
        Av[0] = -__expf(a0.x); Av[1] = -__expf(a0.y); Av[2] = -__expf(a0.z); Av[3] = -__expf(a0.w);
        Av[4] = -__expf(a1.x); Av[5] = -__expf(a1.y); Av[6] = -__expf(a1.z); Av[7] = -__expf(a1.w);
    }

    float s[8];
#pragma unroll
    for (int n = 0; n < 8; n++) s[n] = 0.f;
    float sumdv = 0.f;
    const int t0 = w * 16;
    __syncthreads();

    // phase 1: local segment scan (s_in = 0)
#pragma unroll 4
    for (int tt = 0; tt < 16; tt++) {
        int t = t0 + tt;
        size_t idx = (size_t)(mbase + t) * 2048 + d;
        float dvv = delta[idx];
        float uv  = bf2f(ub[idx]);
        float dvu = dvv * uv;
        sumdv += dvv;
        const float* Brow = &Bsh[t * 16 + h * 8];
#pragma unroll
        for (int n = 0; n < 8; n++) {
            float dA = __expf(dvv * Av[n]);
            s[n] = fmaf(dA, s[n], dvu * Brow[n]);
        }
    }
#pragma unroll
    for (int n = 0; n < 8; n++) sQ[w][dl][h * 8 + n] = s[n];
    if (h == 0) sS[w][dl] = sumdv;
    __syncthreads();

    // phase 2: compose carry from lower segments
    {
        float sin_[8];
#pragma unroll
        for (int n = 0; n < 8; n++) sin_[n] = 0.f;
        float cc = 0.f;
        for (int v = w - 1; v >= 0; v--) {
#pragma unroll
            for (int n = 0; n < 8; n++)
                sin_[n] += __expf(Av[n] * cc) * sQ[v][dl][h * 8 + n];
            cc += sS[v][dl];
        }
#pragma unroll
        for (int n = 0; n < 8; n++) s[n] = sin_[n];
    }

    // phase 3: replay with carry (delta/ub reload is L2-hot), emit gated y
#pragma unroll 2
    for (int tt = 0; tt < 16; tt++) {
        int t = t0 + tt;
        size_t idx = (size_t)(mbase + t) * 2048 + d;
        float dvv = delta[idx];
        float uv  = bf2f(ub[idx]);
        float dvu = dvv * uv;
        const float* Brow = &Bsh[t * 16 + h * 8];
        const float* Crow = &Csh[t * 16 + h * 8];
        float y = 0.f;
#pragma unroll
        for (int n = 0; n < 8; n++) {
            float dA = __expf(dvv * Av[n]);
            s[n] = fmaf(dA, s[n], dvu * Brow[n]);
            y = fmaf(s[n], Crow[n], y);
        }
        y += __shfl_xor(y, 32);
        if (h == 0) {
            float sr = bf2f(sgb[idx]);
            ygb[idx] = f2bf(y * sr);
        }
    }
}

extern "C" void kernel_launch(void* const* d_in, const int* in_sizes, int n_in,
                              void* d_out, int out_size, void* d_ws, size_t ws_size,
                              hipStream_t stream)
{
    const float* x      = (const float*)d_in[0];   // (2,1024,1024) fp32
    const float* W_in   = (const float*)d_in[1];   // (4096,1024)
    const float* b_in   = (const float*)d_in[2];   // (4096,)
    const float* conv_w = (const float*)d_in[3];   // (2048,1,3)
    const float* conv_b = (const float*)d_in[4];   // (2048,)
    const float* W_x    = (const float*)d_in[5];   // (96,2048)
    const float* W_dt   = (const float*)d_in[6];   // (2048,64)
    const float* b_dt   = (const float*)d_in[7];   // (2048,)
    const float* A_log  = (const float*)d_in[8];   // (2048,16)
    const float* W_out  = (const float*)d_in[9];   // (1024,2048)
    const float* b_out  = (const float*)d_in[10];  // (1024,)
    float* out = (float*)d_out;                    // (2,1024,1024) fp32

    // Workspace ~72.3 MB, NO ALIASING (r13 post-mortem: output depended on
    // initial d_ws contents via the xcb/delta alias; every buffer now has
    // exactly one role).
    char* p = (char*)d_ws;
    auto alloc = [&](size_t bytes) { char* r = p; p += (bytes + 255) & ~(size_t)255; return r; };
    ushort_t* xbf    = (ushort_t*)alloc(2048ull * 1024 * 2);   // 4 MB
    ushort_t* winbf  = (ushort_t*)alloc(4096ull * 1024 * 2);   // 8 MB
    ushort_t* wxbf   = (ushort_t*)alloc(96ull * 2048 * 2);
    ushort_t* wdtbf  = (ushort_t*)alloc(2048ull * 64 * 2);
    ushort_t* woutbf = (ushort_t*)alloc(1024ull * 2048 * 2);   // 4 MB
    ushort_t* xcb    = (ushort_t*)alloc(2048ull * 2048 * 2);   // 8 MB  conv input
    float*    delta  = (float*)alloc(2048ull * 2048 * 4);      // 16 MB
    ushort_t* sgb    = (ushort_t*)alloc(2048ull * 2048 * 2);   // 8 MB  silu(res)
    ushort_t* ub     = (ushort_t*)alloc(2048ull * 2048 * 2);   // 8 MB
    float*    xpp    = (float*)alloc(8ull * 2048 * 96 * 4);    // 6.3 MB (split-K=8)
    float*    xp     = (float*)alloc(2048ull * 96 * 4);
    ushort_t* dltb   = (ushort_t*)alloc(2048ull * 64 * 2);
    ushort_t* ygb    = (ushort_t*)alloc(2048ull * 2048 * 2);   // 8 MB

    // 0. round x + weights to bf16
    cvt5<<<8512, 256, 0, stream>>>(x, W_in, W_x, W_dt, W_out,
                                   xbf, winbf, wxbf, wdtbf, woutbf);

    // 1. in_proj: xr = x @ W_in^T + b_in -> xc bf16 | silu(res) bf16.
    //    128x128 tiles, grid (16,32) — r16 showed 128x64 (more blocks but 2x
    //    A-staging traffic) REGRESSES: compute:staging ratio beats occupancy.
    gemm_bt<128, 128, 64, 2, 2, EPI_SPLIT><<<dim3(16, 32), 256, 0, stream>>>(
        xbf, 1024, winbf, 1024, nullptr, sgb, xcb, b_in, 4096, 1024);

    // 2. depthwise causal conv + silu -> ub (bf16)
    conv_silu<<<4096, 256, 0, stream>>>(xcb, conv_w, conv_b, ub);

    // 3. x_proj: xp = u @ W_x^T.  32x96 tiles, split-K=8 -> 512 blocks (2/CU)
    gemm_bt<32, 96, 64, 2, 2, EPI_PARTIAL><<<dim3(64, 1, 8), 256, 0, stream>>>(
        ub, 2048, wxbf, 2048, xpp, nullptr, nullptr, nullptr, 96, 256);

    // 4. reduce partials -> xp fp32, dlt bf16
    xp_reduce<<<768, 256, 0, stream>>>(xpp, xp, dltb);

    // 5. dt_proj: delta = softplus(dlt @ W_dt^T + b_dt) (fp32)
    gemm_bt<64, 64, 64, 2, 2, EPI_SOFTPLUS><<<dim3(32, 32), 256, 0, stream>>>(
        dltb, 64, wdtbf, 64, delta, nullptr, nullptr, b_dt, 2048, 64);

    // 6. two-pass wave-parallel chunked scan + gate -> ygb (bf16)
    scan_kernel<<<dim3(64, 8), 1024, 0, stream>>>(delta, ub, xp, A_log, sgb, ygb);

    // 7. out_proj: out = yg @ W_out^T + b_out (fp32), 64x64 BK=64 -> 512 blocks
    gemm_bt<64, 64, 64, 2, 2, EPI_OUT><<<dim3(32, 16), 256, 0, stream>>>(
        ygb, 2048, woutbf, 2048, out, nullptr, nullptr, b_out, 1024, 2048);
}

// Round 19
// 203.226 us; speedup vs baseline: 1.1029x; 1.0390x over previous
//
#include <hip/hip_runtime.h>
#include <stdint.h>
#include <stddef.h>

typedef __attribute__((ext_vector_type(8))) short short8;
typedef __attribute__((ext_vector_type(4))) float floatx4;
typedef unsigned short ushort_t;

__device__ __forceinline__ ushort_t f2bf(float f) {
    union { float f; uint32_t u; } v; v.f = f;
    return (ushort_t)((v.u + 0x7fffu + ((v.u >> 16) & 1u)) >> 16);
}
__device__ __forceinline__ float bf2f(ushort_t u) {
    union { uint32_t u; float f; } v; v.u = ((uint32_t)u) << 16; return v.f;
}

// async global->LDS 16B staging (m97). LDS dest = wave-uniform base + lane*16.
__device__ __forceinline__ void load16_lds(const ushort_t* g, short* l) {
    __builtin_amdgcn_global_load_lds((const __attribute__((address_space(1))) void*)g,
                                     (__attribute__((address_space(3))) void*)l, 16, 0, 0);
}

enum { EPI_SPLIT = 0, EPI_SOFTPLUS = 1, EPI_OUT = 2, EPI_PARTIAL = 3 };

// Convert x + 4 weights fp32 -> bf16 in one launch.
__global__ __launch_bounds__(256)
void cvt5(const float* __restrict__ x, const float* __restrict__ win,
          const float* __restrict__ wx, const float* __restrict__ wdt,
          const float* __restrict__ wout,
          ushort_t* __restrict__ xb, ushort_t* __restrict__ winb,
          ushort_t* __restrict__ wxb, ushort_t* __restrict__ wdtb,
          ushort_t* __restrict__ woutb)
{
    int g = blockIdx.x * 256 + threadIdx.x;   // < 2179072 exactly
    const float* s; ushort_t* d; int off;
    if      (g < 524288)  { s = x;    d = xb;    off = g; }
    else if (g < 1572864) { s = win;  d = winb;  off = g - 524288; }
    else if (g < 1622016) { s = wx;   d = wxb;   off = g - 1572864; }
    else if (g < 1654784) { s = wdt;  d = wdtb;  off = g - 1622016; }
    else                  { s = wout; d = woutb; off = g - 1654784; }
    float4 v = reinterpret_cast<const float4*>(s)[off];
    union { ushort_t u[4]; uint2 q; } o;
    o.u[0] = f2bf(v.x); o.u[1] = f2bf(v.y); o.u[2] = f2bf(v.z); o.u[3] = f2bf(v.w);
    *reinterpret_cast<uint2*>(d + (size_t)off * 4) = o.q;
}

// C[m,n] = sum_k A[m,k] * B[n,k]  (bf16 operands, fp32 accum)
// LDS BANK-CONFLICT FIX (r17/r18, measured -7 us): row stride BK shorts is a
// multiple of 128 B, so quad lanes (same k, rows 16 apart) collide 16-way.
// Padding impossible (global_load_lds needs tid-contiguous dests) -> XOR-
// swizzle chunk->column: LDS slot (r,j) holds global chunk (r, j^(r&(CPR-1))).
// Write side contiguous, global coalescing unchanged (permutation within the
// row's 16*CPR bytes), read side spans banks 2-way (free per m136).
template<int BM, int BN, int BK, int WR, int WC, int EPI>
__global__ __launch_bounds__(256)
void gemm_bt(const ushort_t* __restrict__ A, int lda,
             const ushort_t* __restrict__ Bw, int ldb,
             float* __restrict__ out0,
             ushort_t* __restrict__ outg,   // EPI_SPLIT gate half (silu bf16)
             ushort_t* __restrict__ outc,   // EPI_SPLIT conv half (bf16)
             const float* __restrict__ bias,
             int N, int kchunk)
{
    constexpr int TM = BM / WR / 16;
    constexpr int TN = BN / WC / 16;
    constexpr int CPR = BK / 8;          // 16B chunks per row
    static_assert(BM % (WR * 16) == 0 && BN % (WC * 16) == 0, "tile");
    static_assert((BM * BK) % 2048 == 0 && (BN * BK) % 2048 == 0, "stage");
    static_assert(BK == 64 || BK == 128, "swizzle assumes CPR = 8 or 16");

    __shared__ __align__(16) short As[BM * BK];
    __shared__ __align__(16) short Bs[BN * BK];

    const int tid  = threadIdx.x;
    const int m0   = blockIdx.x * BM;
    const int n0   = blockIdx.y * BN;
    const int ks   = blockIdx.z;
    const int kbeg = ks * kchunk;

    const int w    = tid >> 6;
    const int lane = tid & 63;
    const int quad = lane >> 4;
    const int l16  = lane & 15;
    const int wr   = w / WC, wc = w % WC;
    const int wm   = wr * (BM / WR);
    const int wn   = wc * (BN / WC);

    floatx4 acc[TM][TN];
#pragma unroll
    for (int i = 0; i < TM; i++)
#pragma unroll
        for (int j = 0; j < TN; j++) acc[i][j] = (floatx4){0.f, 0.f, 0.f, 0.f};

    constexpr int nA = BM * BK / 2048;
    constexpr int nB = BN * BK / 2048;

    for (int kb = kbeg; kb < kbeg + kchunk; kb += BK) {
        __syncthreads();
#pragma unroll
        for (int i = 0; i < nA; i++) {
            int c = i * 256 + tid;
            int r = c / CPR, j = c % CPR;
            int kg = (j ^ (r & (CPR - 1))) * 8;   // swizzled source column
            load16_lds(A + (size_t)(m0 + r) * lda + kb + kg, &As[c * 8]);
        }
#pragma unroll
        for (int i = 0; i < nB; i++) {
            int c = i * 256 + tid;
            int r = c / CPR, j = c % CPR;
            int kg = (j ^ (r & (CPR - 1))) * 8;
            load16_lds(Bw + (size_t)(n0 + r) * ldb + kb + kg, &Bs[c * 8]);
        }
        __syncthreads();
#pragma unroll
        for (int kk = 0; kk < BK / 32; kk++) {
            short8 af[TM], bfr[TN];
#pragma unroll
            for (int t = 0; t < TM; t++) {
                int row = wm + t * 16 + l16;
                int kcc = kk * 4 + quad;
                af[t] = *reinterpret_cast<const short8*>(&As[row * BK + ((kcc ^ (row & (CPR - 1))) * 8)]);
            }
#pragma unroll
            for (int u2 = 0; u2 < TN; u2++) {
                int row = wn + u2 * 16 + l16;
                int kcc = kk * 4 + quad;
                bfr[u2] = *reinterpret_cast<const short8*>(&Bs[row * BK + ((kcc ^ (row & (CPR - 1))) * 8)]);
            }
#pragma unroll
            for (int t = 0; t < TM; t++)
#pragma unroll
                for (int u2 = 0; u2 < TN; u2++)
                    acc[t][u2] = __builtin_amdgcn_mfma_f32_16x16x32_bf16(af[t], bfr[u2], acc[t][u2], 0, 0, 0);
        }
    }

#pragma unroll
    for (int t = 0; t < TM; t++) {
#pragma unroll
        for (int u2 = 0; u2 < TN; u2++) {
#pragma unroll
            for (int r = 0; r < 4; r++) {
                int row = m0 + wm + t * 16 + quad * 4 + r;
                int col = n0 + wn + u2 * 16 + l16;
                float val = acc[t][u2][r];
                if (EPI == EPI_SPLIT) {
                    val += bias[col];
                    if (col < 2048) {
                        outc[(size_t)row * 2048 + col] = f2bf(val);
                    } else {
                        float sr = val / (1.f + __expf(-val));
                        outg[(size_t)row * 2048 + col - 2048] = f2bf(sr);
                    }
                } else if (EPI == EPI_SOFTPLUS) {
                    val += bias[col];
                    float sp = fmaxf(val, 0.f) + __logf(1.f + __expf(-fabsf(val)));
                    out0[(size_t)row * N + col] = sp;
                } else if (EPI == EPI_OUT) {
                    val += bias[col];
                    out0[(size_t)row * N + col] = val;
                } else { // EPI_PARTIAL: split-K partials [ks][m][96]
                    out0[((size_t)ks * 2048 + row) * 96 + col] = val;
                }
            }
        }
    }
}

// depthwise causal conv (k=3) + silu. bf16 in, bf16 out.
__global__ __launch_bounds__(256)
void conv_silu(const ushort_t* __restrict__ xc, const float* __restrict__ cw,
               const float* __restrict__ cb, ushort_t* __restrict__ ub)
{
    int id = blockIdx.x * 256 + threadIdx.x;   // 2048 * 512
    int m  = id >> 9;
    int d4 = (id & 511) * 4;
    int l  = m & 1023;

    union { uint2 q; ushort_t u[4]; } a, b, c;
    a.q = *reinterpret_cast<const uint2*>(xc + (size_t)m * 2048 + d4);
    if (l >= 1) b.q = *reinterpret_cast<const uint2*>(xc + (size_t)(m - 1) * 2048 + d4);
    else        { b.q.x = 0; b.q.y = 0; }
    if (l >= 2) c.q = *reinterpret_cast<const uint2*>(xc + (size_t)(m - 2) * 2048 + d4);
    else        { c.q.x = 0; c.q.y = 0; }

    union { ushort_t u[4]; uint2 q; } o;
#pragma unroll
    for (int j = 0; j < 4; j++) {
        int d = d4 + j;
        float v = cb[d] + cw[d * 3 + 0] * bf2f(c.u[j]) + cw[d * 3 + 1] * bf2f(b.u[j])
                        + cw[d * 3 + 2] * bf2f(a.u[j]);
        o.u[j] = f2bf(v / (1.f + __expf(-v)));
    }
    *reinterpret_cast<uint2*>(ub + (size_t)m * 2048 + d4) = o.q;
}

// reduce split-K=8 partials -> xp fp32 (2048 x 96) and dlt bf16 (2048 x 64)
__global__ __launch_bounds__(256)
void xp_reduce(const float* __restrict__ part, float* __restrict__ xp, ushort_t* __restrict__ dltb)
{
    int e = blockIdx.x * 256 + threadIdx.x;    // < 2048*96 exactly
    float s = 0.f;
#pragma unroll
    for (int ks = 0; ks < 8; ks++) s += part[(size_t)ks * 2048 * 96 + e];
    xp[e] = s;
    int n = e % 96, m = e / 96;
    if (n < 64) dltb[(size_t)m * 64 + n] = f2bf(s);
}

// Chunked selective scan — two-pass structure (28 VGPRs measured, 44.8 us,
// zero bank conflicts). DO NOT add phase-crossing register arrays (r10/r11/
// r12 all spilled to scratch, 8-30x slowdowns).
// r19: Av pre-scaled by log2(e); exp via __builtin_amdgcn_exp2f (1 VALU op
// instead of __expf's mul+exp) — removes ~316 wave-muls/thread.
// Block = 1024 thr = 16 waves, one 256-token chunk x 32 channels.
// lane&31 = channel, lane>>5 = state-half h. Wave w owns t in [16w,16w+16).
__global__ __launch_bounds__(1024, 8)
void scan_kernel(const float* __restrict__ delta, const ushort_t* __restrict__ ub,
                 const float* __restrict__ xp, const float* __restrict__ A_log,
                 const ushort_t* __restrict__ sgb, ushort_t* __restrict__ ygb)
{
    __shared__ __align__(16) float Bsh[256 * 16];
    __shared__ __align__(16) float Csh[256 * 16];
    __shared__ float sQ[16][32][17];
    __shared__ float sS[16][32];

    const int tid  = threadIdx.x;
    const int w    = tid >> 6;                // wave = time segment
    const int lane = tid & 63;
    const int dl   = lane & 31;               // channel within tile
    const int h    = lane >> 5;               // state half
    const int d    = blockIdx.x * 32 + dl;
    const int c    = blockIdx.y;              // (batch<<2)|chunk
    const int mbase = (c >> 2) * 1024 + (c & 3) * 256;

    {   // stage B (xp cols 64..79) / C (80..95): 4 threads per row
        int r = tid >> 2, part = tid & 3;
        const float4* rp = reinterpret_cast<const float4*>(xp + (size_t)(mbase + r) * 96 + 64);
        reinterpret_cast<float4*>(Bsh + r * 16)[part] = rp[part];
        reinterpret_cast<float4*>(Csh + r * 16)[part] = rp[part + 4];
    }

    const float L2E = 1.4426950408889634f;    // log2(e)
    float Av[8];                              // pre-scaled: -exp(A_log)*log2e
    {
        const float4* ap = reinterpret_cast<const float4*>(A_log + (size_t)d * 16 + h * 8);
        float4 a0 = ap[0], a1 = ap[1];
        Av[0] = -__expf(a0.x) * L2E; Av[1] = -__expf(a0.y) * L2E;
        Av[2] = -__expf(a0.z) * L2E; Av[3] = -__expf(a0.w) * L2E;
        Av[4] = -__expf(a1.x) * L2E; Av[5] = -__expf(a1.y) * L2E;
        Av[6] = -__expf(a1.z) * L2E; Av[7] = -__expf(a1.w) * L2E;
    }

    float s[8];
#pragma unroll
    for (int n = 0; n < 8; n++) s[n] = 0.f;
    float sumdv = 0.f;
    const int t0 = w * 16;
    __syncthreads();

    // phase 1: local segment scan (s_in = 0)
#pragma unroll 4
    for (int tt = 0; tt < 16; tt++) {
        int t = t0 + tt;
        size_t idx = (size_t)(mbase + t) * 2048 + d;
        float dvv = delta[idx];
        float uv  = bf2f(ub[idx]);
        float dvu = dvv * uv;
        sumdv += dvv;
        const float* Brow = &Bsh[t * 16 + h * 8];
#pragma unroll
        for (int n = 0; n < 8; n++) {
            float dA = __builtin_amdgcn_exp2f(dvv * Av[n]);
            s[n] = fmaf(dA, s[n], dvu * Brow[n]);
        }
    }
#pragma unroll
    for (int n = 0; n < 8; n++) sQ[w][dl][h * 8 + n] = s[n];
    if (h == 0) sS[w][dl] = sumdv;
    __syncthreads();

    // phase 2: compose carry from lower segments
    {
        float sin_[8];
#pragma unroll
        for (int n = 0; n < 8; n++) sin_[n] = 0.f;
        float cc = 0.f;
        for (int v = w - 1; v >= 0; v--) {
#pragma unroll
            for (int n = 0; n < 8; n++)
                sin_[n] += __builtin_amdgcn_exp2f(Av[n] * cc) * sQ[v][dl][h * 8 + n];
            cc += sS[v][dl];
        }
#pragma unroll
        for (int n = 0; n < 8; n++) s[n] = sin_[n];
    }

    // phase 3: replay with carry (delta/ub reload is L2-hot), emit gated y
#pragma unroll 2
    for (int tt = 0; tt < 16; tt++) {
        int t = t0 + tt;
        size_t idx = (size_t)(mbase + t) * 2048 + d;
        float dvv = delta[idx];
        float uv  = bf2f(ub[idx]);
        float dvu = dvv * uv;
        const float* Brow = &Bsh[t * 16 + h * 8];
        const float* Crow = &Csh[t * 16 + h * 8];
        float y = 0.f;
#pragma unroll
        for (int n = 0; n < 8; n++) {
            float dA = __builtin_amdgcn_exp2f(dvv * Av[n]);
            s[n] = fmaf(dA, s[n], dvu * Brow[n]);
            y = fmaf(s[n], Crow[n], y);
        }
        y += __shfl_xor(y, 32);
        if (h == 0) {
            float sr = bf2f(sgb[idx]);
            ygb[idx] = f2bf(y * sr);
        }
    }
}

extern "C" void kernel_launch(void* const* d_in, const int* in_sizes, int n_in,
                              void* d_out, int out_size, void* d_ws, size_t ws_size,
                              hipStream_t stream)
{
    const float* x      = (const float*)d_in[0];   // (2,1024,1024) fp32
    const float* W_in   = (const float*)d_in[1];   // (4096,1024)
    const float* b_in   = (const float*)d_in[2];   // (4096,)
    const float* conv_w = (const float*)d_in[3];   // (2048,1,3)
    const float* conv_b = (const float*)d_in[4];   // (2048,)
    const float* W_x    = (const float*)d_in[5];   // (96,2048)
    const float* W_dt   = (const float*)d_in[6];   // (2048,64)
    const float* b_dt   = (const float*)d_in[7];   // (2048,)
    const float* A_log  = (const float*)d_in[8];   // (2048,16)
    const float* W_out  = (const float*)d_in[9];   // (1024,2048)
    const float* b_out  = (const float*)d_in[10];  // (1024,)
    float* out = (float*)d_out;                    // (2,1024,1024) fp32

    // Workspace ~72.3 MB, NO ALIASING (r13 post-mortem).
    char* p = (char*)d_ws;
    auto alloc = [&](size_t bytes) { char* r = p; p += (bytes + 255) & ~(size_t)255; return r; };
    ushort_t* xbf    = (ushort_t*)alloc(2048ull * 1024 * 2);   // 4 MB
    ushort_t* winbf  = (ushort_t*)alloc(4096ull * 1024 * 2);   // 8 MB
    ushort_t* wxbf   = (ushort_t*)alloc(96ull * 2048 * 2);
    ushort_t* wdtbf  = (ushort_t*)alloc(2048ull * 64 * 2);
    ushort_t* woutbf = (ushort_t*)alloc(1024ull * 2048 * 2);   // 4 MB
    ushort_t* xcb    = (ushort_t*)alloc(2048ull * 2048 * 2);   // 8 MB  conv input
    float*    delta  = (float*)alloc(2048ull * 2048 * 4);      // 16 MB
    ushort_t* sgb    = (ushort_t*)alloc(2048ull * 2048 * 2);   // 8 MB  silu(res)
    ushort_t* ub     = (ushort_t*)alloc(2048ull * 2048 * 2);   // 8 MB
    float*    xpp    = (float*)alloc(8ull * 2048 * 96 * 4);    // 6.3 MB (split-K=8)
    float*    xp     = (float*)alloc(2048ull * 96 * 4);
    ushort_t* dltb   = (ushort_t*)alloc(2048ull * 64 * 2);
    ushort_t* ygb    = (ushort_t*)alloc(2048ull * 2048 * 2);   // 8 MB

    // 0. round x + weights to bf16
    cvt5<<<8512, 256, 0, stream>>>(x, W_in, W_x, W_dt, W_out,
                                   xbf, winbf, wxbf, wdtbf, woutbf);

    // 1. in_proj: xr = x @ W_in^T + b_in -> xc bf16 | silu(res) bf16.
    //    128x128, BK=128: K-loop 16->8 iters (half the barrier drains).
    //    Grid-limited at 2 blocks/CU so the m132 occupancy penalty of 64 KB
    //    LDS does not apply here.
    gemm_bt<128, 128, 128, 2, 2, EPI_SPLIT><<<dim3(16, 32), 256, 0, stream>>>(
        xbf, 1024, winbf, 1024, nullptr, sgb, xcb, b_in, 4096, 1024);

    // 2. depthwise causal conv + silu -> ub (bf16)
    conv_silu<<<4096, 256, 0, stream>>>(xcb, conv_w, conv_b, ub);

    // 3. x_proj: xp = u @ W_x^T.  32x96 tiles, split-K=8 -> 512 blocks (2/CU)
    gemm_bt<32, 96, 64, 2, 2, EPI_PARTIAL><<<dim3(64, 1, 8), 256, 0, stream>>>(
        ub, 2048, wxbf, 2048, xpp, nullptr, nullptr, nullptr, 96, 256);

    // 4. reduce partials -> xp fp32, dlt bf16
    xp_reduce<<<768, 256, 0, stream>>>(xpp, xp, dltb);

    // 5. dt_proj: delta = softplus(dlt @ W_dt^T + b_dt) (fp32)
    gemm_bt<64, 64, 64, 2, 2, EPI_SOFTPLUS><<<dim3(32, 32), 256, 0, stream>>>(
        dltb, 64, wdtbf, 64, delta, nullptr, nullptr, b_dt, 2048, 64);

    // 6. two-pass wave-parallel chunked scan + gate -> ygb (bf16)
    scan_kernel<<<dim3(64, 8), 1024, 0, stream>>>(delta, ub, xp, A_log, sgb, ygb);

    // 7. out_proj: out = yg @ W_out^T + b_out (fp32), 64x64 BK=64 -> 512 blocks
    gemm_bt<64, 64, 64, 2, 2, EPI_OUT><<<dim3(32, 16), 256, 0, stream>>>(
        ygb, 2048, woutbf, 2048, out, nullptr, nullptr, b_out, 1024, 2048);
}

// Round 20
// 199.979 us; speedup vs baseline: 1.1208x; 1.0162x over previous
//
#include <hip/hip_runtime.h>
#include <stdint.h>
#include <stddef.h>

typedef __attribute__((ext_vector_type(8))) short short8;
typedef __attribute__((ext_vector_type(4))) float floatx4;
typedef unsigned short ushort_t;

__device__ __forceinline__ ushort_t f2bf(float f) {
    union { float f; uint32_t u; } v; v.f = f;
    return (ushort_t)((v.u + 0x7fffu + ((v.u >> 16) & 1u)) >> 16);
}
__device__ __forceinline__ float bf2f(ushort_t u) {
    union { uint32_t u; float f; } v; v.u = ((uint32_t)u) << 16; return v.f;
}

// async global->LDS 16B staging (m97). LDS dest = wave-uniform base + lane*16.
__device__ __forceinline__ void load16_lds(const ushort_t* g, short* l) {
    __builtin_amdgcn_global_load_lds((const __attribute__((address_space(1))) void*)g,
                                     (__attribute__((address_space(3))) void*)l, 16, 0, 0);
}

enum { EPI_SPLIT = 0, EPI_SOFTPLUS = 1, EPI_OUT = 2, EPI_PARTIAL = 3 };

// Convert x + 4 weights fp32 -> bf16 in one launch.
__global__ __launch_bounds__(256)
void cvt5(const float* __restrict__ x, const float* __restrict__ win,
          const float* __restrict__ wx, const float* __restrict__ wdt,
          const float* __restrict__ wout,
          ushort_t* __restrict__ xb, ushort_t* __restrict__ winb,
          ushort_t* __restrict__ wxb, ushort_t* __restrict__ wdtb,
          ushort_t* __restrict__ woutb)
{
    int g = blockIdx.x * 256 + threadIdx.x;   // < 2179072 exactly
    const float* s; ushort_t* d; int off;
    if      (g < 524288)  { s = x;    d = xb;    off = g; }
    else if (g < 1572864) { s = win;  d = winb;  off = g - 524288; }
    else if (g < 1622016) { s = wx;   d = wxb;   off = g - 1572864; }
    else if (g < 1654784) { s = wdt;  d = wdtb;  off = g - 1622016; }
    else                  { s = wout; d = woutb; off = g - 1654784; }
    float4 v = reinterpret_cast<const float4*>(s)[off];
    union { ushort_t u[4]; uint2 q; } o;
    o.u[0] = f2bf(v.x); o.u[1] = f2bf(v.y); o.u[2] = f2bf(v.z); o.u[3] = f2bf(v.w);
    *reinterpret_cast<uint2*>(d + (size_t)off * 4) = o.q;
}

// C[m,n] = sum_k A[m,k] * B[n,k]  (bf16 operands, fp32 accum)
// LDS BANK-CONFLICT FIX (r17/r18, measured -7 us): XOR-swizzle chunk->column
// (LDS slot (r,j) holds global chunk (r, j^(r&(CPR-1)))). Write contiguous,
// coalescing unchanged, reads 2-way (free per m136). Bit-identical results.
// BK=128 on grid-limited kernels (r19: in_proj -4 us): halves barrier drains;
// occupancy unaffected when grid is the limiter.
template<int BM, int BN, int BK, int WR, int WC, int EPI>
__global__ __launch_bounds__(256)
void gemm_bt(const ushort_t* __restrict__ A, int lda,
             const ushort_t* __restrict__ Bw, int ldb,
             float* __restrict__ out0,
             ushort_t* __restrict__ outg,   // EPI_SPLIT gate half (silu bf16)
             ushort_t* __restrict__ outc,   // EPI_SPLIT conv half (bf16)
             const float* __restrict__ bias,
             int N, int kchunk)
{
    constexpr int TM = BM / WR / 16;
    constexpr int TN = BN / WC / 16;
    constexpr int CPR = BK / 8;          // 16B chunks per row
    static_assert(BM % (WR * 16) == 0 && BN % (WC * 16) == 0, "tile");
    static_assert((BM * BK) % 2048 == 0 && (BN * BK) % 2048 == 0, "stage");
    static_assert(BK == 64 || BK == 128, "swizzle assumes CPR = 8 or 16");

    __shared__ __align__(16) short As[BM * BK];
    __shared__ __align__(16) short Bs[BN * BK];

    const int tid  = threadIdx.x;
    const int m0   = blockIdx.x * BM;
    const int n0   = blockIdx.y * BN;
    const int ks   = blockIdx.z;
    const int kbeg = ks * kchunk;

    const int w    = tid >> 6;
    const int lane = tid & 63;
    const int quad = lane >> 4;
    const int l16  = lane & 15;
    const int wr   = w / WC, wc = w % WC;
    const int wm   = wr * (BM / WR);
    const int wn   = wc * (BN / WC);

    floatx4 acc[TM][TN];
#pragma unroll
    for (int i = 0; i < TM; i++)
#pragma unroll
        for (int j = 0; j < TN; j++) acc[i][j] = (floatx4){0.f, 0.f, 0.f, 0.f};

    constexpr int nA = BM * BK / 2048;
    constexpr int nB = BN * BK / 2048;

    for (int kb = kbeg; kb < kbeg + kchunk; kb += BK) {
        __syncthreads();
#pragma unroll
        for (int i = 0; i < nA; i++) {
            int c = i * 256 + tid;
            int r = c / CPR, j = c % CPR;
            int kg = (j ^ (r & (CPR - 1))) * 8;   // swizzled source column
            load16_lds(A + (size_t)(m0 + r) * lda + kb + kg, &As[c * 8]);
        }
#pragma unroll
        for (int i = 0; i < nB; i++) {
            int c = i * 256 + tid;
            int r = c / CPR, j = c % CPR;
            int kg = (j ^ (r & (CPR - 1))) * 8;
            load16_lds(Bw + (size_t)(n0 + r) * ldb + kb + kg, &Bs[c * 8]);
        }
        __syncthreads();
#pragma unroll
        for (int kk = 0; kk < BK / 32; kk++) {
            short8 af[TM], bfr[TN];
#pragma unroll
            for (int t = 0; t < TM; t++) {
                int row = wm + t * 16 + l16;
                int kcc = kk * 4 + quad;
                af[t] = *reinterpret_cast<const short8*>(&As[row * BK + ((kcc ^ (row & (CPR - 1))) * 8)]);
            }
#pragma unroll
            for (int u2 = 0; u2 < TN; u2++) {
                int row = wn + u2 * 16 + l16;
                int kcc = kk * 4 + quad;
                bfr[u2] = *reinterpret_cast<const short8*>(&Bs[row * BK + ((kcc ^ (row & (CPR - 1))) * 8)]);
            }
#pragma unroll
            for (int t = 0; t < TM; t++)
#pragma unroll
                for (int u2 = 0; u2 < TN; u2++)
                    acc[t][u2] = __builtin_amdgcn_mfma_f32_16x16x32_bf16(af[t], bfr[u2], acc[t][u2], 0, 0, 0);
        }
    }

#pragma unroll
    for (int t = 0; t < TM; t++) {
#pragma unroll
        for (int u2 = 0; u2 < TN; u2++) {
#pragma unroll
            for (int r = 0; r < 4; r++) {
                int row = m0 + wm + t * 16 + quad * 4 + r;
                int col = n0 + wn + u2 * 16 + l16;
                float val = acc[t][u2][r];
                if (EPI == EPI_SPLIT) {
                    val += bias[col];
                    if (col < 2048) {
                        outc[(size_t)row * 2048 + col] = f2bf(val);
                    } else {
                        float sr = val / (1.f + __expf(-val));
                        outg[(size_t)row * 2048 + col - 2048] = f2bf(sr);
                    }
                } else if (EPI == EPI_SOFTPLUS) {
                    val += bias[col];
                    float sp = fmaxf(val, 0.f) + __logf(1.f + __expf(-fabsf(val)));
                    out0[(size_t)row * N + col] = sp;
                } else if (EPI == EPI_OUT) {
                    val += bias[col];
                    out0[(size_t)row * N + col] = val;
                } else { // EPI_PARTIAL: split-K partials [ks][m][96]
                    out0[((size_t)ks * 2048 + row) * 96 + col] = val;
                }
            }
        }
    }
}

// depthwise causal conv (k=3) + silu. bf16 in, bf16 out.
__global__ __launch_bounds__(256)
void conv_silu(const ushort_t* __restrict__ xc, const float* __restrict__ cw,
               const float* __restrict__ cb, ushort_t* __restrict__ ub)
{
    int id = blockIdx.x * 256 + threadIdx.x;   // 2048 * 512
    int m  = id >> 9;
    int d4 = (id & 511) * 4;
    int l  = m & 1023;

    union { uint2 q; ushort_t u[4]; } a, b, c;
    a.q = *reinterpret_cast<const uint2*>(xc + (size_t)m * 2048 + d4);
    if (l >= 1) b.q = *reinterpret_cast<const uint2*>(xc + (size_t)(m - 1) * 2048 + d4);
    else        { b.q.x = 0; b.q.y = 0; }
    if (l >= 2) c.q = *reinterpret_cast<const uint2*>(xc + (size_t)(m - 2) * 2048 + d4);
    else        { c.q.x = 0; c.q.y = 0; }

    union { ushort_t u[4]; uint2 q; } o;
#pragma unroll
    for (int j = 0; j < 4; j++) {
        int d = d4 + j;
        float v = cb[d] + cw[d * 3 + 0] * bf2f(c.u[j]) + cw[d * 3 + 1] * bf2f(b.u[j])
                        + cw[d * 3 + 2] * bf2f(a.u[j]);
        o.u[j] = f2bf(v / (1.f + __expf(-v)));
    }
    *reinterpret_cast<uint2*>(ub + (size_t)m * 2048 + d4) = o.q;
}

// reduce split-K=8 partials -> xp fp32 (2048 x 96) and dlt bf16 (2048 x 64)
__global__ __launch_bounds__(256)
void xp_reduce(const float* __restrict__ part, float* __restrict__ xp, ushort_t* __restrict__ dltb)
{
    int e = blockIdx.x * 256 + threadIdx.x;    // < 2048*96 exactly
    float s = 0.f;
#pragma unroll
    for (int ks = 0; ks < 8; ks++) s += part[(size_t)ks * 2048 * 96 + e];
    xp[e] = s;
    int n = e % 96, m = e / 96;
    if (n < 64) dltb[(size_t)m * 64 + n] = f2bf(s);
}

// Chunked selective scan — two-pass structure (28 VGPRs measured, zero bank
// conflicts). DO NOT add phase-crossing register arrays (r10/r11/r12 all
// spilled to scratch, 8-30x slowdowns). exp via exp2f with pre-scaled Av
// (r19, -2 us). Block = 1024 thr = 16 waves, one 256-token chunk x 32
// channels. lane&31 = channel, lane>>5 = state-half h. Wave w owns
// t in [16w,16w+16).
__global__ __launch_bounds__(1024, 8)
void scan_kernel(const float* __restrict__ delta, const ushort_t* __restrict__ ub,
                 const float* __restrict__ xp, const float* __restrict__ A_log,
                 const ushort_t* __restrict__ sgb, ushort_t* __restrict__ ygb)
{
    __shared__ __align__(16) float Bsh[256 * 16];
    __shared__ __align__(16) float Csh[256 * 16];
    __shared__ float sQ[16][32][17];
    __shared__ float sS[16][32];

    const int tid  = threadIdx.x;
    const int w    = tid >> 6;                // wave = time segment
    const int lane = tid & 63;
    const int dl   = lane & 31;               // channel within tile
    const int h    = lane >> 5;               // state half
    const int d    = blockIdx.x * 32 + dl;
    const int c    = blockIdx.y;              // (batch<<2)|chunk
    const int mbase = (c >> 2) * 1024 + (c & 3) * 256;

    {   // stage B (xp cols 64..79) / C (80..95): 4 threads per row
        int r = tid >> 2, part = tid & 3;
        const float4* rp = reinterpret_cast<const float4*>(xp + (size_t)(mbase + r) * 96 + 64);
        reinterpret_cast<float4*>(Bsh + r * 16)[part] = rp[part];
        reinterpret_cast<float4*>(Csh + r * 16)[part] = rp[part + 4];
    }

    const float L2E = 1.4426950408889634f;    // log2(e)
    float Av[8];                              // pre-scaled: -exp(A_log)*log2e
    {
        const float4* ap = reinterpret_cast<const float4*>(A_log + (size_t)d * 16 + h * 8);
        float4 a0 = ap[0], a1 = ap[1];
        Av[0] = -__expf(a0.x) * L2E; Av[1] = -__expf(a0.y) * L2E;
        Av[2] = -__expf(a0.z) * L2E; Av[3] = -__expf(a0.w) * L2E;
        Av[4] = -__expf(a1.x) * L2E; Av[5] = -__expf(a1.y) * L2E;
        Av[6] = -__expf(a1.z) * L2E; Av[7] = -__expf(a1.w) * L2E;
    }

    float s[8];
#pragma unroll
    for (int n = 0; n < 8; n++) s[n] = 0.f;
    float sumdv = 0.f;
    const int t0 = w * 16;
    __syncthreads();

    // phase 1: local segment scan (s_in = 0)
#pragma unroll 4
    for (int tt = 0; tt < 16; tt++) {
        int t = t0 + tt;
        size_t idx = (size_t)(mbase + t) * 2048 + d;
        float dvv = delta[idx];
        float uv  = bf2f(ub[idx]);
        float dvu = dvv * uv;
        sumdv += dvv;
        const float* Brow = &Bsh[t * 16 + h * 8];
#pragma unroll
        for (int n = 0; n < 8; n++) {
            float dA = __builtin_amdgcn_exp2f(dvv * Av[n]);
            s[n] = fmaf(dA, s[n], dvu * Brow[n]);
        }
    }
#pragma unroll
    for (int n = 0; n < 8; n++) sQ[w][dl][h * 8 + n] = s[n];
    if (h == 0) sS[w][dl] = sumdv;
    __syncthreads();

    // phase 2: compose carry from lower segments
    {
        float sin_[8];
#pragma unroll
        for (int n = 0; n < 8; n++) sin_[n] = 0.f;
        float cc = 0.f;
        for (int v = w - 1; v >= 0; v--) {
#pragma unroll
            for (int n = 0; n < 8; n++)
                sin_[n] += __builtin_amdgcn_exp2f(Av[n] * cc) * sQ[v][dl][h * 8 + n];
            cc += sS[v][dl];
        }
#pragma unroll
        for (int n = 0; n < 8; n++) s[n] = sin_[n];
    }

    // phase 3: replay with carry (delta/ub reload is L2-hot), emit gated y
#pragma unroll 2
    for (int tt = 0; tt < 16; tt++) {
        int t = t0 + tt;
        size_t idx = (size_t)(mbase + t) * 2048 + d;
        float dvv = delta[idx];
        float uv  = bf2f(ub[idx]);
        float dvu = dvv * uv;
        const float* Brow = &Bsh[t * 16 + h * 8];
        const float* Crow = &Csh[t * 16 + h * 8];
        float y = 0.f;
#pragma unroll
        for (int n = 0; n < 8; n++) {
            float dA = __builtin_amdgcn_exp2f(dvv * Av[n]);
            s[n] = fmaf(dA, s[n], dvu * Brow[n]);
            y = fmaf(s[n], Crow[n], y);
        }
        y += __shfl_xor(y, 32);
        if (h == 0) {
            float sr = bf2f(sgb[idx]);
            ygb[idx] = f2bf(y * sr);
        }
    }
}

extern "C" void kernel_launch(void* const* d_in, const int* in_sizes, int n_in,
                              void* d_out, int out_size, void* d_ws, size_t ws_size,
                              hipStream_t stream)
{
    const float* x      = (const float*)d_in[0];   // (2,1024,1024) fp32
    const float* W_in   = (const float*)d_in[1];   // (4096,1024)
    const float* b_in   = (const float*)d_in[2];   // (4096,)
    const float* conv_w = (const float*)d_in[3];   // (2048,1,3)
    const float* conv_b = (const float*)d_in[4];   // (2048,)
    const float* W_x    = (const float*)d_in[5];   // (96,2048)
    const float* W_dt   = (const float*)d_in[6];   // (2048,64)
    const float* b_dt   = (const float*)d_in[7];   // (2048,)
    const float* A_log  = (const float*)d_in[8];   // (2048,16)
    const float* W_out  = (const float*)d_in[9];   // (1024,2048)
    const float* b_out  = (const float*)d_in[10];  // (1024,)
    float* out = (float*)d_out;                    // (2,1024,1024) fp32

    // Workspace ~72.3 MB, NO ALIASING (r13 post-mortem).
    char* p = (char*)d_ws;
    auto alloc = [&](size_t bytes) { char* r = p; p += (bytes + 255) & ~(size_t)255; return r; };
    ushort_t* xbf    = (ushort_t*)alloc(2048ull * 1024 * 2);   // 4 MB
    ushort_t* winbf  = (ushort_t*)alloc(4096ull * 1024 * 2);   // 8 MB
    ushort_t* wxbf   = (ushort_t*)alloc(96ull * 2048 * 2);
    ushort_t* wdtbf  = (ushort_t*)alloc(2048ull * 64 * 2);
    ushort_t* woutbf = (ushort_t*)alloc(1024ull * 2048 * 2);   // 4 MB
    ushort_t* xcb    = (ushort_t*)alloc(2048ull * 2048 * 2);   // 8 MB  conv input
    float*    delta  = (float*)alloc(2048ull * 2048 * 4);      // 16 MB
    ushort_t* sgb    = (ushort_t*)alloc(2048ull * 2048 * 2);   // 8 MB  silu(res)
    ushort_t* ub     = (ushort_t*)alloc(2048ull * 2048 * 2);   // 8 MB
    float*    xpp    = (float*)alloc(8ull * 2048 * 96 * 4);    // 6.3 MB (split-K=8)
    float*    xp     = (float*)alloc(2048ull * 96 * 4);
    ushort_t* dltb   = (ushort_t*)alloc(2048ull * 64 * 2);
    ushort_t* ygb    = (ushort_t*)alloc(2048ull * 2048 * 2);   // 8 MB

    // 0. round x + weights to bf16
    cvt5<<<8512, 256, 0, stream>>>(x, W_in, W_x, W_dt, W_out,
                                   xbf, winbf, wxbf, wdtbf, woutbf);

    // 1. in_proj: xr = x @ W_in^T + b_in -> xc bf16 | silu(res) bf16.
    //    128x128, BK=128 (r19: -4 us; grid-limited so 64 KB LDS is free).
    gemm_bt<128, 128, 128, 2, 2, EPI_SPLIT><<<dim3(16, 32), 256, 0, stream>>>(
        xbf, 1024, winbf, 1024, nullptr, sgb, xcb, b_in, 4096, 1024);

    // 2. depthwise causal conv + silu -> ub (bf16)
    conv_silu<<<4096, 256, 0, stream>>>(xcb, conv_w, conv_b, ub);

    // 3. x_proj: xp = u @ W_x^T.  32x96 tiles, split-K=8 -> 512 blocks (2/CU)
    gemm_bt<32, 96, 64, 2, 2, EPI_PARTIAL><<<dim3(64, 1, 8), 256, 0, stream>>>(
        ub, 2048, wxbf, 2048, xpp, nullptr, nullptr, nullptr, 96, 256);

    // 4. reduce partials -> xp fp32, dlt bf16
    xp_reduce<<<768, 256, 0, stream>>>(xpp, xp, dltb);

    // 5. dt_proj: delta = softplus(dlt @ W_dt^T + b_dt) (fp32)
    gemm_bt<64, 64, 64, 2, 2, EPI_SOFTPLUS><<<dim3(32, 32), 256, 0, stream>>>(
        dltb, 64, wdtbf, 64, delta, nullptr, nullptr, b_dt, 2048, 64);

    // 6. two-pass wave-parallel chunked scan + gate -> ygb (bf16)
    scan_kernel<<<dim3(64, 8), 1024, 0, stream>>>(delta, ub, xp, A_log, sgb, ygb);

    // 7. out_proj: out = yg @ W_out^T + b_out (fp32).  BK=128: K-loop 32->16
    //    iters (same mechanism as in_proj r19 win; grid-limited 2 blocks/CU
    //    so 32 KB LDS costs nothing). Accumulation order unchanged.
    gemm_bt<64, 64, 128, 2, 2, EPI_OUT><<<dim3(32, 16), 256, 0, stream>>>(
        ygb, 2048, woutbf, 2048, out, nullptr, nullptr, b_out, 1024, 2048);
}

// Round 21
// 198.170 us; speedup vs baseline: 1.1311x; 1.0091x over previous
//
#include <hip/hip_runtime.h>
#include <stdint.h>
#include <stddef.h>

typedef __attribute__((ext_vector_type(8))) short short8;
typedef __attribute__((ext_vector_type(4))) float floatx4;
typedef unsigned short ushort_t;

__device__ __forceinline__ ushort_t f2bf(float f) {
    union { float f; uint32_t u; } v; v.f = f;
    return (ushort_t)((v.u + 0x7fffu + ((v.u >> 16) & 1u)) >> 16);
}
__device__ __forceinline__ float bf2f(ushort_t u) {
    union { uint32_t u; float f; } v; v.u = ((uint32_t)u) << 16; return v.f;
}

// async global->LDS 16B staging (m97). LDS dest = wave-uniform base + lane*16.
__device__ __forceinline__ void load16_lds(const ushort_t* g, short* l) {
    __builtin_amdgcn_global_load_lds((const __attribute__((address_space(1))) void*)g,
                                     (__attribute__((address_space(3))) void*)l, 16, 0, 0);
}

enum { EPI_SPLIT = 0, EPI_SOFTPLUS_PACK = 1, EPI_OUT = 2, EPI_PARTIAL = 3 };

// Convert x + 4 weights fp32 -> bf16 in one launch.
__global__ __launch_bounds__(256)
void cvt5(const float* __restrict__ x, const float* __restrict__ win,
          const float* __restrict__ wx, const float* __restrict__ wdt,
          const float* __restrict__ wout,
          ushort_t* __restrict__ xb, ushort_t* __restrict__ winb,
          ushort_t* __restrict__ wxb, ushort_t* __restrict__ wdtb,
          ushort_t* __restrict__ woutb)
{
    int g = blockIdx.x * 256 + threadIdx.x;   // < 2179072 exactly
    const float* s; ushort_t* d; int off;
    if      (g < 524288)  { s = x;    d = xb;    off = g; }
    else if (g < 1572864) { s = win;  d = winb;  off = g - 524288; }
    else if (g < 1622016) { s = wx;   d = wxb;   off = g - 1572864; }
    else if (g < 1654784) { s = wdt;  d = wdtb;  off = g - 1622016; }
    else                  { s = wout; d = woutb; off = g - 1654784; }
    float4 v = reinterpret_cast<const float4*>(s)[off];
    union { ushort_t u[4]; uint2 q; } o;
    o.u[0] = f2bf(v.x); o.u[1] = f2bf(v.y); o.u[2] = f2bf(v.z); o.u[3] = f2bf(v.w);
    *reinterpret_cast<uint2*>(d + (size_t)off * 4) = o.q;
}

// C[m,n] = sum_k A[m,k] * B[n,k]  (bf16 operands, fp32 accum)
// LDS bank-conflict fix (r17/r18, -7 us): XOR-swizzle chunk->column. BK=128
// on grid-limited kernels (r19/r20, -7 us combined): halves barrier drains.
template<int BM, int BN, int BK, int WR, int WC, int EPI>
__global__ __launch_bounds__(256)
void gemm_bt(const ushort_t* __restrict__ A, int lda,
             const ushort_t* __restrict__ Bw, int ldb,
             float* __restrict__ out0,
             ushort_t* __restrict__ outg,   // SPLIT: gate out | SOFTPLUS_PACK: ub in
             ushort_t* __restrict__ outc,   // SPLIT: conv half out (bf16)
             const float* __restrict__ bias,
             int N, int kchunk)
{
    constexpr int TM = BM / WR / 16;
    constexpr int TN = BN / WC / 16;
    constexpr int CPR = BK / 8;          // 16B chunks per row
    static_assert(BM % (WR * 16) == 0 && BN % (WC * 16) == 0, "tile");
    static_assert((BM * BK) % 2048 == 0 && (BN * BK) % 2048 == 0, "stage");
    static_assert(BK == 64 || BK == 128, "swizzle assumes CPR = 8 or 16");

    __shared__ __align__(16) short As[BM * BK];
    __shared__ __align__(16) short Bs[BN * BK];

    const int tid  = threadIdx.x;
    const int m0   = blockIdx.x * BM;
    const int n0   = blockIdx.y * BN;
    const int ks   = blockIdx.z;
    const int kbeg = ks * kchunk;

    const int w    = tid >> 6;
    const int lane = tid & 63;
    const int quad = lane >> 4;
    const int l16  = lane & 15;
    const int wr   = w / WC, wc = w % WC;
    const int wm   = wr * (BM / WR);
    const int wn   = wc * (BN / WC);

    floatx4 acc[TM][TN];
#pragma unroll
    for (int i = 0; i < TM; i++)
#pragma unroll
        for (int j = 0; j < TN; j++) acc[i][j] = (floatx4){0.f, 0.f, 0.f, 0.f};

    constexpr int nA = BM * BK / 2048;
    constexpr int nB = BN * BK / 2048;

    for (int kb = kbeg; kb < kbeg + kchunk; kb += BK) {
        __syncthreads();
#pragma unroll
        for (int i = 0; i < nA; i++) {
            int c = i * 256 + tid;
            int r = c / CPR, j = c % CPR;
            int kg = (j ^ (r & (CPR - 1))) * 8;   // swizzled source column
            load16_lds(A + (size_t)(m0 + r) * lda + kb + kg, &As[c * 8]);
        }
#pragma unroll
        for (int i = 0; i < nB; i++) {
            int c = i * 256 + tid;
            int r = c / CPR, j = c % CPR;
            int kg = (j ^ (r & (CPR - 1))) * 8;
            load16_lds(Bw + (size_t)(n0 + r) * ldb + kb + kg, &Bs[c * 8]);
        }
        __syncthreads();
#pragma unroll
        for (int kk = 0; kk < BK / 32; kk++) {
            short8 af[TM], bfr[TN];
#pragma unroll
            for (int t = 0; t < TM; t++) {
                int row = wm + t * 16 + l16;
                int kcc = kk * 4 + quad;
                af[t] = *reinterpret_cast<const short8*>(&As[row * BK + ((kcc ^ (row & (CPR - 1))) * 8)]);
            }
#pragma unroll
            for (int u2 = 0; u2 < TN; u2++) {
                int row = wn + u2 * 16 + l16;
                int kcc = kk * 4 + quad;
                bfr[u2] = *reinterpret_cast<const short8*>(&Bs[row * BK + ((kcc ^ (row & (CPR - 1))) * 8)]);
            }
#pragma unroll
            for (int t = 0; t < TM; t++)
#pragma unroll
                for (int u2 = 0; u2 < TN; u2++)
                    acc[t][u2] = __builtin_amdgcn_mfma_f32_16x16x32_bf16(af[t], bfr[u2], acc[t][u2], 0, 0, 0);
        }
    }

#pragma unroll
    for (int t = 0; t < TM; t++) {
#pragma unroll
        for (int u2 = 0; u2 < TN; u2++) {
#pragma unroll
            for (int r = 0; r < 4; r++) {
                int row = m0 + wm + t * 16 + quad * 4 + r;
                int col = n0 + wn + u2 * 16 + l16;
                float val = acc[t][u2][r];
                if (EPI == EPI_SPLIT) {
                    val += bias[col];
                    if (col < 2048) {
                        outc[(size_t)row * 2048 + col] = f2bf(val);
                    } else {
                        float sr = val / (1.f + __expf(-val));
                        outg[(size_t)row * 2048 + col - 2048] = f2bf(sr);
                    }
                } else if (EPI == EPI_SOFTPLUS_PACK) {
                    // delta = softplus(val); pack (bf16(delta)<<16)|ub for the
                    // scan's single-dword per-timestep load (r21: halves scan
                    // global-load count; bf16 delta within error budget).
                    val += bias[col];
                    float sp = fmaxf(val, 0.f) + __logf(1.f + __expf(-fabsf(val)));
                    uint32_t pk = ((uint32_t)f2bf(sp) << 16)
                                | (uint32_t)outg[(size_t)row * N + col];
                    reinterpret_cast<uint32_t*>(out0)[(size_t)row * N + col] = pk;
                } else if (EPI == EPI_OUT) {
                    val += bias[col];
                    out0[(size_t)row * N + col] = val;
                } else { // EPI_PARTIAL: split-K partials [ks][m][96]
                    out0[((size_t)ks * 2048 + row) * 96 + col] = val;
                }
            }
        }
    }
}

// depthwise causal conv (k=3) + silu. bf16 in, bf16 out.
__global__ __launch_bounds__(256)
void conv_silu(const ushort_t* __restrict__ xc, const float* __restrict__ cw,
               const float* __restrict__ cb, ushort_t* __restrict__ ub)
{
    int id = blockIdx.x * 256 + threadIdx.x;   // 2048 * 512
    int m  = id >> 9;
    int d4 = (id & 511) * 4;
    int l  = m & 1023;

    union { uint2 q; ushort_t u[4]; } a, b, c;
    a.q = *reinterpret_cast<const uint2*>(xc + (size_t)m * 2048 + d4);
    if (l >= 1) b.q = *reinterpret_cast<const uint2*>(xc + (size_t)(m - 1) * 2048 + d4);
    else        { b.q.x = 0; b.q.y = 0; }
    if (l >= 2) c.q = *reinterpret_cast<const uint2*>(xc + (size_t)(m - 2) * 2048 + d4);
    else        { c.q.x = 0; c.q.y = 0; }

    union { ushort_t u[4]; uint2 q; } o;
#pragma unroll
    for (int j = 0; j < 4; j++) {
        int d = d4 + j;
        float v = cb[d] + cw[d * 3 + 0] * bf2f(c.u[j]) + cw[d * 3 + 1] * bf2f(b.u[j])
                        + cw[d * 3 + 2] * bf2f(a.u[j]);
        o.u[j] = f2bf(v / (1.f + __expf(-v)));
    }
    *reinterpret_cast<uint2*>(ub + (size_t)m * 2048 + d4) = o.q;
}

// reduce split-K=8 partials -> xp fp32 (2048 x 96) and dlt bf16 (2048 x 64)
__global__ __launch_bounds__(256)
void xp_reduce(const float* __restrict__ part, float* __restrict__ xp, ushort_t* __restrict__ dltb)
{
    int e = blockIdx.x * 256 + threadIdx.x;    // < 2048*96 exactly
    float s = 0.f;
#pragma unroll
    for (int ks = 0; ks < 8; ks++) s += part[(size_t)ks * 2048 * 96 + e];
    xp[e] = s;
    int n = e % 96, m = e / 96;
    if (n < 64) dltb[(size_t)m * 64 + n] = f2bf(s);
}

// Chunked selective scan — two-pass structure (28 VGPRs, zero bank conflicts).
// DO NOT add phase-crossing register arrays (r10/r11/r12 spilled, 8-30x).
// r19: exp2f with pre-scaled Av. r21: delta+u packed in one dword (from
// dt_proj) -> 1 global load per timestep per pass instead of 2.
// Block = 1024 thr = 16 waves, one 256-token chunk x 32 channels.
// lane&31 = channel, lane>>5 = state-half h. Wave w owns t in [16w,16w+16).
__global__ __launch_bounds__(1024, 8)
void scan_kernel(const uint32_t* __restrict__ dup,
                 const float* __restrict__ xp, const float* __restrict__ A_log,
                 const ushort_t* __restrict__ sgb, ushort_t* __restrict__ ygb)
{
    __shared__ __align__(16) float Bsh[256 * 16];
    __shared__ __align__(16) float Csh[256 * 16];
    __shared__ float sQ[16][32][17];
    __shared__ float sS[16][32];

    const int tid  = threadIdx.x;
    const int w    = tid >> 6;                // wave = time segment
    const int lane = tid & 63;
    const int dl   = lane & 31;               // channel within tile
    const int h    = lane >> 5;               // state half
    const int d    = blockIdx.x * 32 + dl;
    const int c    = blockIdx.y;              // (batch<<2)|chunk
    const int mbase = (c >> 2) * 1024 + (c & 3) * 256;

    {   // stage B (xp cols 64..79) / C (80..95): 4 threads per row
        int r = tid >> 2, part = tid & 3;
        const float4* rp = reinterpret_cast<const float4*>(xp + (size_t)(mbase + r) * 96 + 64);
        reinterpret_cast<float4*>(Bsh + r * 16)[part] = rp[part];
        reinterpret_cast<float4*>(Csh + r * 16)[part] = rp[part + 4];
    }

    const float L2E = 1.4426950408889634f;    // log2(e)
    float Av[8];                              // pre-scaled: -exp(A_log)*log2e
    {
        const float4* ap = reinterpret_cast<const float4*>(A_log + (size_t)d * 16 + h * 8);
        float4 a0 = ap[0], a1 = ap[1];
        Av[0] = -__expf(a0.x) * L2E; Av[1] = -__expf(a0.y) * L2E;
        Av[2] = -__expf(a0.z) * L2E; Av[3] = -__expf(a0.w) * L2E;
        Av[4] = -__expf(a1.x) * L2E; Av[5] = -__expf(a1.y) * L2E;
        Av[6] = -__expf(a1.z) * L2E; Av[7] = -__expf(a1.w) * L2E;
    }

    float s[8];
#pragma unroll
    for (int n = 0; n < 8; n++) s[n] = 0.f;
    float sumdv = 0.f;
    const int t0 = w * 16;
    __syncthreads();

    // phase 1: local segment scan (s_in = 0)
#pragma unroll 4
    for (int tt = 0; tt < 16; tt++) {
        int t = t0 + tt;
        size_t idx = (size_t)(mbase + t) * 2048 + d;
        uint32_t pk = dup[idx];
        union { uint32_t u; float f; } dv_, uv_;
        dv_.u = pk & 0xFFFF0000u; uv_.u = pk << 16;
        float dvv = dv_.f;
        float dvu = dvv * uv_.f;
        sumdv += dvv;
        const float* Brow = &Bsh[t * 16 + h * 8];
#pragma unroll
        for (int n = 0; n < 8; n++) {
            float dA = __builtin_amdgcn_exp2f(dvv * Av[n]);
            s[n] = fmaf(dA, s[n], dvu * Brow[n]);
        }
    }
#pragma unroll
    for (int n = 0; n < 8; n++) sQ[w][dl][h * 8 + n] = s[n];
    if (h == 0) sS[w][dl] = sumdv;
    __syncthreads();

    // phase 2: compose carry from lower segments
    {
        float sin_[8];
#pragma unroll
        for (int n = 0; n < 8; n++) sin_[n] = 0.f;
        float cc = 0.f;
        for (int v = w - 1; v >= 0; v--) {
#pragma unroll
            for (int n = 0; n < 8; n++)
                sin_[n] += __builtin_amdgcn_exp2f(Av[n] * cc) * sQ[v][dl][h * 8 + n];
            cc += sS[v][dl];
        }
#pragma unroll
        for (int n = 0; n < 8; n++) s[n] = sin_[n];
    }

    // phase 3: replay with carry (packed reload is L2-hot), emit gated y
#pragma unroll 2
    for (int tt = 0; tt < 16; tt++) {
        int t = t0 + tt;
        size_t idx = (size_t)(mbase + t) * 2048 + d;
        uint32_t pk = dup[idx];
        union { uint32_t u; float f; } dv_, uv_;
        dv_.u = pk & 0xFFFF0000u; uv_.u = pk << 16;
        float dvv = dv_.f;
        float dvu = dvv * uv_.f;
        const float* Brow = &Bsh[t * 16 + h * 8];
        const float* Crow = &Csh[t * 16 + h * 8];
        float y = 0.f;
#pragma unroll
        for (int n = 0; n < 8; n++) {
            float dA = __builtin_amdgcn_exp2f(dvv * Av[n]);
            s[n] = fmaf(dA, s[n], dvu * Brow[n]);
            y = fmaf(s[n], Crow[n], y);
        }
        y += __shfl_xor(y, 32);
        if (h == 0) {
            float sr = bf2f(sgb[idx]);
            ygb[idx] = f2bf(y * sr);
        }
    }
}

extern "C" void kernel_launch(void* const* d_in, const int* in_sizes, int n_in,
                              void* d_out, int out_size, void* d_ws, size_t ws_size,
                              hipStream_t stream)
{
    const float* x      = (const float*)d_in[0];   // (2,1024,1024) fp32
    const float* W_in   = (const float*)d_in[1];   // (4096,1024)
    const float* b_in   = (const float*)d_in[2];   // (4096,)
    const float* conv_w = (const float*)d_in[3];   // (2048,1,3)
    const float* conv_b = (const float*)d_in[4];   // (2048,)
    const float* W_x    = (const float*)d_in[5];   // (96,2048)
    const float* W_dt   = (const float*)d_in[6];   // (2048,64)
    const float* b_dt   = (const float*)d_in[7];   // (2048,)
    const float* A_log  = (const float*)d_in[8];   // (2048,16)
    const float* W_out  = (const float*)d_in[9];   // (1024,2048)
    const float* b_out  = (const float*)d_in[10];  // (1024,)
    float* out = (float*)d_out;                    // (2,1024,1024) fp32

    // Workspace ~72.3 MB, NO ALIASING (r13 post-mortem).
    char* p = (char*)d_ws;
    auto alloc = [&](size_t bytes) { char* r = p; p += (bytes + 255) & ~(size_t)255; return r; };
    ushort_t* xbf    = (ushort_t*)alloc(2048ull * 1024 * 2);   // 4 MB
    ushort_t* winbf  = (ushort_t*)alloc(4096ull * 1024 * 2);   // 8 MB
    ushort_t* wxbf   = (ushort_t*)alloc(96ull * 2048 * 2);
    ushort_t* wdtbf  = (ushort_t*)alloc(2048ull * 64 * 2);
    ushort_t* woutbf = (ushort_t*)alloc(1024ull * 2048 * 2);   // 4 MB
    ushort_t* xcb    = (ushort_t*)alloc(2048ull * 2048 * 2);   // 8 MB  conv input
    uint32_t* dup    = (uint32_t*)alloc(2048ull * 2048 * 4);   // 16 MB packed delta|u
    ushort_t* sgb    = (ushort_t*)alloc(2048ull * 2048 * 2);   // 8 MB  silu(res)
    ushort_t* ub     = (ushort_t*)alloc(2048ull * 2048 * 2);   // 8 MB
    float*    xpp    = (float*)alloc(8ull * 2048 * 96 * 4);    // 6.3 MB (split-K=8)
    float*    xp     = (float*)alloc(2048ull * 96 * 4);
    ushort_t* dltb   = (ushort_t*)alloc(2048ull * 64 * 2);
    ushort_t* ygb    = (ushort_t*)alloc(2048ull * 2048 * 2);   // 8 MB

    // 0. round x + weights to bf16
    cvt5<<<8512, 256, 0, stream>>>(x, W_in, W_x, W_dt, W_out,
                                   xbf, winbf, wxbf, wdtbf, woutbf);

    // 1. in_proj: xr = x @ W_in^T + b_in -> xc bf16 | silu(res) bf16.
    //    128x128, BK=128 (r19: -4 us; grid-limited so 64 KB LDS is free).
    gemm_bt<128, 128, 128, 2, 2, EPI_SPLIT><<<dim3(16, 32), 256, 0, stream>>>(
        xbf, 1024, winbf, 1024, nullptr, sgb, xcb, b_in, 4096, 1024);

    // 2. depthwise causal conv + silu -> ub (bf16)
    conv_silu<<<4096, 256, 0, stream>>>(xcb, conv_w, conv_b, ub);

    // 3. x_proj: xp = u @ W_x^T.  32x96 tiles, split-K=8 -> 512 blocks (2/CU)
    gemm_bt<32, 96, 64, 2, 2, EPI_PARTIAL><<<dim3(64, 1, 8), 256, 0, stream>>>(
        ub, 2048, wxbf, 2048, xpp, nullptr, nullptr, nullptr, 96, 256);

    // 4. reduce partials -> xp fp32, dlt bf16
    xp_reduce<<<768, 256, 0, stream>>>(xpp, xp, dltb);

    // 5. dt_proj: delta = softplus(dlt @ W_dt^T + b_dt), packed with ub
    //    into dup (bf16 delta << 16 | bf16 u) for the scan.
    gemm_bt<64, 64, 64, 2, 2, EPI_SOFTPLUS_PACK><<<dim3(32, 32), 256, 0, stream>>>(
        dltb, 64, wdtbf, 64, (float*)dup, ub, nullptr, b_dt, 2048, 64);

    // 6. two-pass wave-parallel chunked scan + gate -> ygb (bf16)
    scan_kernel<<<dim3(64, 8), 1024, 0, stream>>>(dup, xp, A_log, sgb, ygb);

    // 7. out_proj: out = yg @ W_out^T + b_out (fp32), 64x64 BK=128 (r20: -3 us)
    gemm_bt<64, 64, 128, 2, 2, EPI_OUT><<<dim3(32, 16), 256, 0, stream>>>(
        ygb, 2048, woutbf, 2048, out, nullptr, nullptr, b_out, 1024, 2048);
}